// Round 4
// baseline (694.009 us; speedup 1.0000x reference)
//
#include <hip/hip_runtime.h>
#include <hip/hip_cooperative_groups.h>
#include <math.h>

namespace cg = cooperative_groups;

#define T_TOK 4096
#define A_DIM 1024
#define E_DIM 512
#define N_SPAN 32768
#define W_MAX 10
#define HID 150
#define FD 20

#define PR  160             // P row stride (bf16 elems); cols 150..159 zero
#define KP2 160             // padded K/N for the 150x150 layers

// ---- workspace layout (float offsets) ----
#define WS_ATTNS 0
#define WS_PB    4096
#define WS_WPACK 1314816
#define WS_SB    1627856
#define WS_EB    3725008
// Pb ushort offsets
#define PB_P0 0
#define PB_P1 655360
#define PB_P2 1310720
#define PB_P3 1966080
// wpack ushort offsets
#define WP_ST  0
#define WP_V   491520
#define WP_A2  573440
#define WP_S2  599040
#define WP_WE1 624640
#define WP_TOTAL 626080
#define SB_PIECES 524288     // 4096*1024/8
#define EB_PIECES 262144     // 4096*512/8
#define PK_ITEMS (WP_TOTAL + SB_PIECES + EB_PIECES)

#define GRID_BLOCKS 1024
#define BLOCK_THREADS 128

typedef short  bf16x8 __attribute__((ext_vector_type(8)));
typedef float  f32x4  __attribute__((ext_vector_type(4)));

__device__ __forceinline__ float4 ld4(const float* p) { return *(const float4*)p; }

__device__ __forceinline__ unsigned short f2bf(float f) {
    unsigned u = __float_as_uint(f);
    unsigned r = u + 0x7fffu + ((u >> 16) & 1u);   // RNE
    return (unsigned short)(r >> 16);
}
__device__ __forceinline__ float bf2f(short s) {
    return __uint_as_float(((unsigned)(unsigned short)s) << 16);
}
__device__ __forceinline__ bf16x8 cvt_frag(const float* p) {
    float4 u = ld4(p), v = ld4(p + 4);
    bf16x8 f;
    f[0] = (short)f2bf(u.x); f[1] = (short)f2bf(u.y);
    f[2] = (short)f2bf(u.z); f[3] = (short)f2bf(u.w);
    f[4] = (short)f2bf(v.x); f[5] = (short)f2bf(v.y);
    f[6] = (short)f2bf(v.z); f[7] = (short)f2bf(v.w);
    return f;
}

// ---------------------------------------------------------------------------
// All-register M=32 GEMM half-strip (one wave, K split across 2 waves).
// Per chunk: 7 coalesced 16B/lane register loads (2 A-frags + 5 B-frags),
// 10 MFMA. No LDS, no dma, no ds_read: compiler auto-pipelines (depth-2
// double-buffered frags, waitcnt inserted per-register).
// ---------------------------------------------------------------------------
template<int NCH>
__device__ __forceinline__ void gemm_reg(
    const unsigned short* __restrict__ pA0, const unsigned short* __restrict__ pA1,
    const unsigned short* __restrict__ pB, f32x4 (&acc)[2][5])
{
    bf16x8 a0[2], a1[2], bb[2][5];
#define LDC(c, s) { \
        a0[s] = *(const bf16x8*)(pA0 + (size_t)(c) * 512); \
        a1[s] = *(const bf16x8*)(pA1 + (size_t)(c) * 512); \
        _Pragma("unroll") \
        for (int t = 0; t < 5; ++t) \
            bb[s][t] = *(const bf16x8*)(pB + (size_t)(c) * 2560 + t * 512); }
    LDC(0, 0);
#pragma unroll
    for (int c = 0; c < NCH; ++c) {
        const int s = c & 1;
        if (c + 1 < NCH) LDC(c + 1, s ^ 1);
#pragma unroll
        for (int t = 0; t < 5; ++t) {
            acc[0][t] = __builtin_amdgcn_mfma_f32_16x16x32_bf16(a0[s], bb[s][t], acc[0][t], 0, 0, 0);
            acc[1][t] = __builtin_amdgcn_mfma_f32_16x16x32_bf16(a1[s], bb[s][t], acc[1][t], 0, 0, 0);
        }
    }
#undef LDC
}

// ---------------------------------------------------------------------------
// ONE cooperative kernel: prepack -> token GEMM -> attn tail -> span.
// 1024 blocks x 128 thr (2 waves), 13.6 KB LDS arena, 4+ blocks/CU resident.
// ---------------------------------------------------------------------------
__global__ __launch_bounds__(BLOCK_THREADS, 2) void mega_kernel(
    const float* __restrict__ states, const float* __restrict__ embeds,
    const int* __restrict__ span_starts, const int* __restrict__ span_widths,
    const float* __restrict__ Wa1, const float* __restrict__ ba1,
    const float* __restrict__ Wa2, const float* __restrict__ ba2,
    const float* __restrict__ Wa3, const float* __restrict__ ba3,
    const float* __restrict__ width_emb,
    const float* __restrict__ Ws1, const float* __restrict__ bs1,
    const float* __restrict__ Ws2, const float* __restrict__ bs2,
    const float* __restrict__ Ws3, const float* __restrict__ bs3,
    float* __restrict__ out, float* __restrict__ attns,
    unsigned short* __restrict__ Pb, unsigned short* __restrict__ wp,
    unsigned short* __restrict__ Sb, unsigned short* __restrict__ Eb)
{
    __shared__ __align__(16) unsigned char arena[14336];
    cg::grid_group grid = cg::this_grid();
    const int tid = threadIdx.x;

    // ================= phase P: prepack (grid-stride) =================
    for (int idx = blockIdx.x * BLOCK_THREADS + tid; idx < PK_ITEMS;
         idx += GRID_BLOCKS * BLOCK_THREADS) {
        if (idx < WP_TOTAL) {
            float v = 0.f;
            if (idx < WP_V) {                               // ST: 3 x 2 x 32 x 2560
                int gidx = idx / 163840, r = idx % 163840;
                int ngrp = r / 81920, r2 = r % 81920;
                int c = r2 / 2560, d = r2 % 2560;
                int n = d >> 5, qsw = (d >> 3) & 3, off = d & 7;
                int q = qsw ^ ((n >> 1) & 3);
                int k = c * 32 + q * 8 + off;
                int gn = ngrp * 80 + n;
                const float* W = (gidx == 0) ? Wa1 : Ws1 + (size_t)(gidx - 1) * 1024 * HID;
                if (gn < HID) v = W[(size_t)k * HID + gn];
            } else if (idx < WP_A2) {                       // V: 2 x 16 x 2560
                int r = idx - WP_V;
                int ngrp = r / 40960, r2 = r % 40960;
                int c = r2 / 2560, d = r2 % 2560;
                int n = d >> 5, qsw = (d >> 3) & 3, off = d & 7;
                int q = qsw ^ ((n >> 1) & 3);
                int k = c * 32 + q * 8 + off;
                int gn = ngrp * 80 + n;
                if (gn < HID) v = Ws1[(size_t)(2048 + k) * HID + gn];
            } else if (idx < WP_S2) {                       // Wa2 [n][160]
                int e = idx - WP_A2;
                int n = e / KP2, k = e % KP2;
                if (n < HID && k < HID) v = Wa2[(size_t)k * HID + n];
            } else if (idx < WP_WE1) {                      // Ws2 [n][160]
                int e = idx - WP_S2;
                int n = e / KP2, k = e % KP2;
                if (n < HID && k < HID) v = Ws2[(size_t)k * HID + n];
            } else {                                        // WE1 [9][160]
                int e = idx - WP_WE1;
                int b = e / KP2, n = e % KP2;
                if (n < HID)
                    for (int k = 0; k < FD; ++k)
                        v = fmaf(width_emb[b * FD + k], Ws1[(size_t)(2560 + k) * HID + n], v);
            }
            wp[idx] = f2bf(v);
        } else if (idx < WP_TOTAL + SB_PIECES) {            // Sb piece (8 elems)
            int p = idx - WP_TOTAL;
            int mb = p >> 11, r = p & 2047;
            int c = r >> 6, d8 = r & 63;
            int m = d8 >> 2, qsw = d8 & 3;
            int q = qsw ^ ((m >> 1) & 3);
            const float* src = states + (size_t)(mb * 16 + m) * A_DIM + c * 32 + q * 8;
            *(bf16x8*)(Sb + (size_t)p * 8) = cvt_frag(src);
        } else {                                            // Eb piece
            int p = idx - WP_TOTAL - SB_PIECES;
            int mb = p >> 10, r = p & 1023;
            int c = r >> 6, d8 = r & 63;
            int m = d8 >> 2, qsw = d8 & 3;
            int q = qsw ^ ((m >> 1) & 3);
            const float* src = embeds + (size_t)(mb * 16 + m) * E_DIM + c * 32 + q * 8;
            *(bf16x8*)(Eb + (size_t)p * 8) = cvt_frag(src);
        }
    }
    __threadfence();
    grid.sync();

    // ================= phase A: token GEMM (M=32/wave, K-split x2) ======
    {
        const int wv = tid >> 6;
        const int lane = tid & 63, l15 = lane & 15, quad = lane >> 4;
        const int bl = l15 * 32 + ((quad ^ ((l15 >> 1) & 3)) * 8);
        const int task = blockIdx.x;

        f32x4 acc[2][5];
#pragma unroll
        for (int mt = 0; mt < 2; ++mt)
#pragma unroll
            for (int t = 0; t < 5; ++t)
#pragma unroll
                for (int i = 0; i < 4; ++i) acc[mt][t][i] = 0.f;

        int mb32, gidx, ngrp;
        if (task < 768) {
            mb32 = task / 6;
            const int sub = task % 6;
            gidx = sub >> 1;             // 0:Wa1->P0, 1:Ws1a->P1, 2:Ws1b->P2
            ngrp = sub & 1;
            const unsigned short* pA0 = Sb + (size_t)(mb32 * 2)     * 16384 + wv * 16 * 512 + bl;
            const unsigned short* pA1 = Sb + (size_t)(mb32 * 2 + 1) * 16384 + wv * 16 * 512 + bl;
            const unsigned short* pB  = wp + WP_ST + gidx * 163840 + ngrp * 81920
                                           + wv * 16 * 2560 + bl;
            gemm_reg<16>(pA0, pA1, pB, acc);
        } else {
            const int e = task - 768;
            mb32 = e >> 1; ngrp = e & 1; gidx = 3;   // V -> P3
            const unsigned short* pA0 = Eb + (size_t)(mb32 * 2)     * 8192 + wv * 8 * 512 + bl;
            const unsigned short* pA1 = Eb + (size_t)(mb32 * 2 + 1) * 8192 + wv * 8 * 512 + bl;
            const unsigned short* pB  = wp + WP_V + ngrp * 40960 + wv * 8 * 2560 + bl;
            gemm_reg<8>(pA0, pA1, pB, acc);
        }

        // K-split reduce (wave1 -> LDS, wave0 sums + writes P)
        float* red = (float*)arena;
        if (wv == 1) {
#pragma unroll
            for (int mt = 0; mt < 2; ++mt)
#pragma unroll
                for (int t = 0; t < 5; ++t)
#pragma unroll
                    for (int i = 0; i < 4; ++i)
                        red[((mt * 5 + t) * 4 + i) * 64 + lane] = acc[mt][t][i];
        }
        __syncthreads();
        if (wv == 0) {
            unsigned short* Pg = Pb + (size_t)gidx * 655360;
#pragma unroll
            for (int mt = 0; mt < 2; ++mt)
#pragma unroll
                for (int t = 0; t < 5; ++t) {
                    const int col = ngrp * 80 + t * 16 + l15;
#pragma unroll
                    for (int i = 0; i < 4; ++i) {
                        const float v = acc[mt][t][i] +
                                        red[((mt * 5 + t) * 4 + i) * 64 + lane];
                        Pg[(size_t)(mb32 * 32 + mt * 16 + quad * 4 + i) * PR + col] =
                            (col < HID) ? f2bf(v) : (unsigned short)0;
                    }
                }
        }
    }
    __threadfence();
    grid.sync();

    // ================= phase B: attention tail (blocks 0..127) ==========
    if (blockIdx.x < 128) {
        const int wv = tid >> 6;
        const int lane = tid & 63, l15 = lane & 15, quad = lane >> 4;
        const int t0 = (blockIdx.x * 2 + wv) * 16;
        const unsigned short* P0 = Pb + PB_P0;

        f32x4 acc[10];
#pragma unroll
        for (int nt = 0; nt < 10; ++nt)
#pragma unroll
            for (int i = 0; i < 4; ++i) acc[nt][i] = 0.f;

        const unsigned short* prow = P0 + (size_t)(t0 + l15) * PR;
        const unsigned short* bb = wp + WP_A2 + l15 * KP2 + quad * 8;

#pragma unroll
        for (int c = 0; c < 5; ++c) {
            const int k0 = c * 32;
            const int kk = k0 + quad * 8;
            bf16x8 raw = *(const bf16x8*)(prow + kk);
            bf16x8 af;
#pragma unroll
            for (int j = 0; j < 8; ++j) {
                const float b = (kk + j < HID) ? ba1[kk + j] : 0.f;
                af[j] = (short)f2bf(fmaxf(bf2f(raw[j]) + b, 0.f));
            }
#pragma unroll
            for (int nt = 0; nt < 10; ++nt) {
                bf16x8 bf = *(const bf16x8*)(bb + nt * 16 * KP2 + k0);
                acc[nt] = __builtin_amdgcn_mfma_f32_16x16x32_bf16(af, bf, acc[nt], 0, 0, 0);
            }
        }

        float sc[4] = {0.f, 0.f, 0.f, 0.f};
#pragma unroll
        for (int nt = 0; nt < 10; ++nt) {
            const int col = nt * 16 + l15;
            const float w3 = (col < HID) ? Wa3[col] : 0.f;
            const float b2 = (col < HID) ? ba2[col] : 0.f;
#pragma unroll
            for (int i = 0; i < 4; ++i)
                sc[i] = fmaf(fmaxf(acc[nt][i] + b2, 0.f), w3, sc[i]);
        }
#pragma unroll
        for (int off = 8; off >= 1; off >>= 1)
#pragma unroll
            for (int i = 0; i < 4; ++i) sc[i] += __shfl_down(sc[i], off, 16);
        if (l15 == 0) {
            const float b3 = ba3[0];
#pragma unroll
            for (int i = 0; i < 4; ++i) attns[t0 + quad * 4 + i] = sc[i] + b3;
        }
    }
    __threadfence();
    grid.sync();

    // ================= phase C: span scoring (32 spans/block) ===========
    {
        unsigned short (*sHb)[168] = (unsigned short (*)[168])arena;     // 10752 B
        float (*s_wgt)[W_MAX]      = (float (*)[W_MAX])(arena + 10752);  //  1280 B
        int*   s_st  = (int*)(arena + 12032);
        int*   s_wd  = (int*)(arena + 12160);
        int*   s_bin = (int*)(arena + 12288);
        int*   s_oid = (int*)(arena + 12416);
        int*   s_wdr = (int*)(arena + 12544);
        float (*sPart)[32] = (float (*)[32])(arena + 12672);             //   256 B
        float* sb1 = (float*)(arena + 12928);                            //   640 B

        const int n0s = blockIdx.x * 32;
        for (int j = tid; j < KP2; j += BLOCK_THREADS)
            sb1[j] = (j < HID) ? bs1[j] : 0.f;
        int st = 0, wd = 0;
        if (tid < 32) {
            st = span_starts[n0s + tid];
            wd = span_widths[n0s + tid];
            s_wdr[tid] = wd;
        }
        __syncthreads();
        if (tid < 32) {
            int rank = 0;
#pragma unroll
            for (int j = 0; j < 32; ++j) {
                const int wj = s_wdr[j];
                rank += (wj < wd) || (wj == wd && j < tid);
            }
            s_st[rank] = st; s_wd[rank] = wd; s_oid[rank] = tid;
            s_bin[rank] = (wd >= 1) + (wd >= 2) + (wd >= 3) + (wd >= 4) +
                          (wd >= 8) + (wd >= 16) + (wd >= 32) + (wd >= 64);
            float lg[W_MAX];
            float m = -1e30f;
#pragma unroll
            for (int w = 0; w < W_MAX; ++w)
                if (w < wd) { float a = attns[st + w]; lg[w] = a; m = fmaxf(m, a); }
            float sum = 0.f;
#pragma unroll
            for (int w = 0; w < W_MAX; ++w) {
                float e = (w < wd) ? __expf(lg[w] - m) : 0.f;
                lg[w] = e; sum += e;
            }
            float inv = 1.f / sum;
#pragma unroll
            for (int w = 0; w < W_MAX; ++w) s_wgt[rank][w] = lg[w] * inv;
        }
        __syncthreads();

        // gather-combine: 4 lanes/span, bf16x8 chunks (spans width-sorted)
        {
            const unsigned short* P1b = Pb + PB_P1;
            const unsigned short* P2b = Pb + PB_P2;
            const unsigned short* P3b = Pb + PB_P3;
            const unsigned short* WEb = wp + WP_WE1;
            const int s = tid >> 2, jl = tid & 3;
            const int sst = s_st[s], swd = s_wd[s];
            const size_t rs = (size_t)sst * PR;
            const size_t re = (size_t)(sst + swd - 1) * PR;
            const size_t rb = (size_t)s_bin[s] * PR;
            for (int c = jl; c < 20; c += 4) {
                const int j = c * 8;
                bf16x8 u1 = *(const bf16x8*)(P1b + rs + j);
                bf16x8 u2 = *(const bf16x8*)(P2b + re + j);
                bf16x8 uw = *(const bf16x8*)(WEb + rb + j);
                float acc[8];
#pragma unroll
                for (int i = 0; i < 8; ++i)
                    acc[i] = bf2f(u1[i]) + bf2f(u2[i]) + bf2f(uw[i]) + sb1[j + i];
#pragma unroll
                for (int w = 0; w < W_MAX; ++w) {
                    if (w < swd) {
                        float wt = s_wgt[s][w];
                        bf16x8 uv = *(const bf16x8*)(P3b + rs + (size_t)w * PR + j);
#pragma unroll
                        for (int i = 0; i < 8; ++i)
                            acc[i] = fmaf(wt, bf2f(uv[i]), acc[i]);
                    }
                }
                bf16x8 pk;
#pragma unroll
                for (int i = 0; i < 8; ++i) pk[i] = (short)f2bf(fmaxf(acc[i], 0.f));
                *(bf16x8*)&sHb[s][j] = pk;
            }
        }
        __syncthreads();

        // layer2 MFMA: M=32 (2 m-tiles), N=160 split 5 n-tiles per wave
        const int wv = tid >> 6, lane = tid & 63, l15 = lane & 15, quad = lane >> 4;
        const int nb = wv * 5;

        f32x4 a2[2][5];
#pragma unroll
        for (int mt = 0; mt < 2; ++mt)
#pragma unroll
            for (int t = 0; t < 5; ++t)
#pragma unroll
                for (int i = 0; i < 4; ++i) a2[mt][t][i] = 0.f;

#pragma unroll
        for (int c = 0; c < 5; ++c) {
            const int k0 = c * 32;
            bf16x8 af0 = *(const bf16x8*)&sHb[l15][k0 + quad * 8];
            bf16x8 af1 = *(const bf16x8*)&sHb[16 + l15][k0 + quad * 8];
#pragma unroll
            for (int t = 0; t < 5; ++t) {
                bf16x8 b = *(const bf16x8*)(wp + WP_S2 +
                            (size_t)((nb + t) * 16 + l15) * KP2 + k0 + quad * 8);
                a2[0][t] = __builtin_amdgcn_mfma_f32_16x16x32_bf16(af0, b, a2[0][t], 0, 0, 0);
                a2[1][t] = __builtin_amdgcn_mfma_f32_16x16x32_bf16(af1, b, a2[1][t], 0, 0, 0);
            }
        }

        float sc[2][4];
#pragma unroll
        for (int mt = 0; mt < 2; ++mt)
#pragma unroll
            for (int i = 0; i < 4; ++i) sc[mt][i] = 0.f;
#pragma unroll
        for (int t = 0; t < 5; ++t) {
            const int col = (nb + t) * 16 + l15;
            const float w3 = (col < HID) ? Ws3[col] : 0.f;
            const float b2 = (col < HID) ? bs2[col] : 0.f;
#pragma unroll
            for (int mt = 0; mt < 2; ++mt)
#pragma unroll
                for (int i = 0; i < 4; ++i)
                    sc[mt][i] = fmaf(fmaxf(a2[mt][t][i] + b2, 0.f), w3, sc[mt][i]);
        }
#pragma unroll
        for (int off = 8; off >= 1; off >>= 1)
#pragma unroll
            for (int mt = 0; mt < 2; ++mt)
#pragma unroll
                for (int i = 0; i < 4; ++i)
                    sc[mt][i] += __shfl_down(sc[mt][i], off, 16);
        if (l15 == 0) {
#pragma unroll
            for (int mt = 0; mt < 2; ++mt)
#pragma unroll
                for (int i = 0; i < 4; ++i)
                    sPart[wv][mt * 16 + quad * 4 + i] = sc[mt][i];
        }
        __syncthreads();
        if (tid < 32)
            out[n0s + s_oid[tid]] = sPart[0][tid] + sPart[1][tid] + bs3[0];
    }
}

// ---------------------------------------------------------------------------
extern "C" void kernel_launch(void* const* d_in, const int* in_sizes, int n_in,
                              void* d_out, int out_size, void* d_ws, size_t ws_size,
                              hipStream_t stream)
{
    const float* states      = (const float*)d_in[0];
    const float* embeds      = (const float*)d_in[1];
    const int*   span_starts = (const int*)d_in[2];
    const int*   span_widths = (const int*)d_in[3];
    const float* Wa1 = (const float*)d_in[4];
    const float* ba1 = (const float*)d_in[5];
    const float* Wa2 = (const float*)d_in[6];
    const float* ba2 = (const float*)d_in[7];
    const float* Wa3 = (const float*)d_in[8];
    const float* ba3 = (const float*)d_in[9];
    const float* width_emb = (const float*)d_in[10];
    const float* Ws1 = (const float*)d_in[11];
    const float* bs1 = (const float*)d_in[12];
    const float* Ws2 = (const float*)d_in[13];
    const float* bs2 = (const float*)d_in[14];
    const float* Ws3 = (const float*)d_in[15];
    const float* bs3 = (const float*)d_in[16];
    float* out = (float*)d_out;

    float* ws    = (float*)d_ws;
    float* attns = ws + WS_ATTNS;
    unsigned short* Pb    = (unsigned short*)(ws + WS_PB);
    unsigned short* wpack = (unsigned short*)(ws + WS_WPACK);
    unsigned short* Sb    = (unsigned short*)(ws + WS_SB);
    unsigned short* Eb    = (unsigned short*)(ws + WS_EB);

    void* kargs[] = {
        (void*)&states, (void*)&embeds, (void*)&span_starts, (void*)&span_widths,
        (void*)&Wa1, (void*)&ba1, (void*)&Wa2, (void*)&ba2, (void*)&Wa3, (void*)&ba3,
        (void*)&width_emb, (void*)&Ws1, (void*)&bs1, (void*)&Ws2, (void*)&bs2,
        (void*)&Ws3, (void*)&bs3, (void*)&out, (void*)&attns, (void*)&Pb, (void*)&wpack,
        (void*)&Sb, (void*)&Eb };

    hipLaunchCooperativeKernel((void*)mega_kernel, dim3(GRID_BLOCKS),
                               dim3(BLOCK_THREADS), kargs, 0, stream);
}

// Round 5
// 158.439 us; speedup vs baseline: 4.3803x; 4.3803x over previous
//
#include <hip/hip_runtime.h>
#include <math.h>

#define T_TOK 4096
#define A_DIM 1024
#define E_DIM 512
#define N_SPAN 32768
#define W_MAX 10
#define HID 150
#define FD 20

#define PR  160             // P row stride (bf16 elems); cols 150..159 zero
#define KP2 160             // padded K/N for the 150x150 layers

// ---- workspace layout (float offsets) ----
#define WS_ATTNS 0
#define WS_PB    4096
#define WS_WPACK 1314816
#define WS_SB    1627856
#define WS_EB    3725008
// Pb ushort offsets
#define PB_P0 0
#define PB_P1 655360
#define PB_P2 1310720
#define PB_P3 1966080
// wpack ushort offsets
//   ST: [3 gidx][2 ngrp][32 c][2560]  (chunk-contiguous, XOR-swizzled)
//   V : [2 ngrp][16 c][2560]
//   A2/S2: [160 n][160 k] n-major;  WE1: [9][160]
#define WP_ST  0
#define WP_V   491520
#define WP_A2  573440
#define WP_S2  599040
#define WP_WE1 624640
#define WP_TOTAL 626080
#define SB_PIECES 524288     // 4096*1024/8
#define EB_PIECES 262144     // 4096*512/8
#define PK_ITEMS (WP_TOTAL + SB_PIECES + EB_PIECES)

typedef short  bf16x8 __attribute__((ext_vector_type(8)));
typedef float  f32x4  __attribute__((ext_vector_type(4)));

__device__ __forceinline__ float4 ld4(const float* p) { return *(const float4*)p; }

__device__ __forceinline__ unsigned short f2bf(float f) {
    unsigned u = __float_as_uint(f);
    unsigned r = u + 0x7fffu + ((u >> 16) & 1u);   // RNE
    return (unsigned short)(r >> 16);
}
__device__ __forceinline__ float bf2f(short s) {
    return __uint_as_float(((unsigned)(unsigned short)s) << 16);
}
__device__ __forceinline__ bf16x8 cvt_frag(const float* p) {
    float4 u = ld4(p), v = ld4(p + 4);
    bf16x8 f;
    f[0] = (short)f2bf(u.x); f[1] = (short)f2bf(u.y);
    f[2] = (short)f2bf(u.z); f[3] = (short)f2bf(u.w);
    f[4] = (short)f2bf(v.x); f[5] = (short)f2bf(v.y);
    f[6] = (short)f2bf(v.z); f[7] = (short)f2bf(v.w);
    return f;
}

// ---------------------------------------------------------------------------
// Prepack (dst-linear, coalesced writes): weights + Sb/Eb bf16 staging.
// ---------------------------------------------------------------------------
__global__ __launch_bounds__(256) void prepack_kernel(
    const float* __restrict__ states, const float* __restrict__ embeds,
    const float* __restrict__ Wa1, const float* __restrict__ Ws1,
    const float* __restrict__ Wa2, const float* __restrict__ Ws2,
    const float* __restrict__ width_emb,
    unsigned short* __restrict__ wp, unsigned short* __restrict__ Sb,
    unsigned short* __restrict__ Eb)
{
    int idx = blockIdx.x * 256 + threadIdx.x;
    if (idx >= PK_ITEMS) return;
    if (idx < WP_TOTAL) {
        float v = 0.f;
        if (idx < WP_V) {                               // ST: 3 x 2 x 32 x 2560
            int gidx = idx / 163840, r = idx % 163840;
            int ngrp = r / 81920, r2 = r % 81920;
            int c = r2 / 2560, d = r2 % 2560;
            int n = d >> 5, qsw = (d >> 3) & 3, off = d & 7;
            int q = qsw ^ ((n >> 1) & 3);
            int k = c * 32 + q * 8 + off;
            int gn = ngrp * 80 + n;
            const float* W = (gidx == 0) ? Wa1 : Ws1 + (size_t)(gidx - 1) * 1024 * HID;
            if (gn < HID) v = W[(size_t)k * HID + gn];
        } else if (idx < WP_A2) {                       // V: 2 x 16 x 2560
            int r = idx - WP_V;
            int ngrp = r / 40960, r2 = r % 40960;
            int c = r2 / 2560, d = r2 % 2560;
            int n = d >> 5, qsw = (d >> 3) & 3, off = d & 7;
            int q = qsw ^ ((n >> 1) & 3);
            int k = c * 32 + q * 8 + off;
            int gn = ngrp * 80 + n;
            if (gn < HID) v = Ws1[(size_t)(2048 + k) * HID + gn];
        } else if (idx < WP_S2) {                       // Wa2 [n][160]
            int e = idx - WP_A2;
            int n = e / KP2, k = e % KP2;
            if (n < HID && k < HID) v = Wa2[(size_t)k * HID + n];
        } else if (idx < WP_WE1) {                      // Ws2 [n][160]
            int e = idx - WP_S2;
            int n = e / KP2, k = e % KP2;
            if (n < HID && k < HID) v = Ws2[(size_t)k * HID + n];
        } else {                                        // WE1 [9][160]
            int e = idx - WP_WE1;
            int b = e / KP2, n = e % KP2;
            if (n < HID)
                for (int k = 0; k < FD; ++k)
                    v = fmaf(width_emb[b * FD + k], Ws1[(size_t)(2560 + k) * HID + n], v);
        }
        wp[idx] = f2bf(v);
    } else if (idx < WP_TOTAL + SB_PIECES) {            // Sb piece (8 elems)
        int p = idx - WP_TOTAL;
        int mb = p >> 11, r = p & 2047;                 // 2048 pieces per 16-row tile
        int c = r >> 6, d8 = r & 63;
        int m = d8 >> 2, qsw = d8 & 3;
        int q = qsw ^ ((m >> 1) & 3);
        const float* src = states + (size_t)(mb * 16 + m) * A_DIM + c * 32 + q * 8;
        *(bf16x8*)(Sb + (size_t)p * 8) = cvt_frag(src);
    } else {                                            // Eb piece
        int p = idx - WP_TOTAL - SB_PIECES;
        int mb = p >> 10, r = p & 1023;                 // 1024 pieces per tile
        int c = r >> 6, d8 = r & 63;
        int m = d8 >> 2, qsw = d8 & 3;
        int q = qsw ^ ((m >> 1) & 3);
        const float* src = embeds + (size_t)(mb * 16 + m) * E_DIM + c * 32 + q * 8;
        *(bf16x8*)(Eb + (size_t)p * 8) = cvt_frag(src);
    }
}

// ---------------------------------------------------------------------------
// All-register M=64 GEMM strip: one wave owns 4 m-tiles x 80 cols x full K.
// Per chunk: 9 coalesced 16B/lane register loads (4 A + 5 B), 20 MFMA.
// B frags amortized over 4 m-tiles -> 4x less B traffic than M=16 strips.
// Depth-2 double-buffered register pipeline (compiler-scheduled waitcnt).
// ---------------------------------------------------------------------------
template<int NC, int ATILE>
__device__ __forceinline__ void gemm_m64(
    const unsigned short* __restrict__ pA,   // pre-offset by bl
    const unsigned short* __restrict__ pB,   // pre-offset by bl
    f32x4 (&acc)[4][5])
{
    bf16x8 a[2][4], bb[2][5];
#define LDC(c, s) { _Pragma("unroll") \
        for (int mt = 0; mt < 4; ++mt) \
            a[s][mt] = *(const bf16x8*)(pA + (size_t)mt * ATILE + (size_t)(c) * 512); \
        _Pragma("unroll") \
        for (int t = 0; t < 5; ++t) \
            bb[s][t] = *(const bf16x8*)(pB + (size_t)(c) * 2560 + t * 512); }
    LDC(0, 0);
#pragma unroll
    for (int c = 0; c < NC; ++c) {
        const int s = c & 1;
        if (c + 1 < NC) LDC(c + 1, s ^ 1);
#pragma unroll
        for (int mt = 0; mt < 4; ++mt)
#pragma unroll
            for (int t = 0; t < 5; ++t)
                acc[mt][t] = __builtin_amdgcn_mfma_f32_16x16x32_bf16(
                                 a[s][mt], bb[s][t], acc[mt][t], 0, 0, 0);
    }
#undef LDC
}

// ---------------------------------------------------------------------------
// Token kernel: 512 blocks x 64 threads (1 wave, M=64 rows each, no LDS).
// XCD-aware task mapping (round-robin blockIdx%8 = XCD): each XCD owns
// m-groups {x, 8+x, .., 56+x} for ALL 6 weight panels -> per-XCD working
// set = 1.5 MB A + 1.1 MB B < 4 MB L2 (kills the L3 thrash seen in R2).
//   b <  384 : b = x + 8*(s + 6*g) : mg=g*8+x, gidx=s>>1, ngrp=s&1 (K=1024)
//   b >= 384 : e = x + 8*(s + 2*g) : mg=g*8+x, gidx=3,     ngrp=s   (K=512)
// ---------------------------------------------------------------------------
__global__ __launch_bounds__(64) void token_kernel(
    const unsigned short* __restrict__ Sb, const unsigned short* __restrict__ Eb,
    const unsigned short* __restrict__ wp, unsigned short* __restrict__ Pb)
{
    const int lane = threadIdx.x, l15 = lane & 15, quad = lane >> 4;
    const int bl = l15 * 32 + ((quad ^ ((l15 >> 1) & 3)) * 8);
    const int b = blockIdx.x;

    f32x4 acc[4][5];
#pragma unroll
    for (int mt = 0; mt < 4; ++mt)
#pragma unroll
        for (int t = 0; t < 5; ++t)
#pragma unroll
            for (int i = 0; i < 4; ++i) acc[mt][t][i] = 0.f;

    int mg, gidx, ngrp;
    if (b < 384) {
        const int x = b & 7, r = b >> 3;      // r in [0,48)
        const int s = r % 6, g = r / 6;       // g in [0,8)
        mg = g * 8 + x; gidx = s >> 1; ngrp = s & 1;
        const unsigned short* pA = Sb + (size_t)mg * 4 * 16384 + bl;
        const unsigned short* pB = wp + WP_ST + gidx * 163840 + ngrp * 81920 + bl;
        gemm_m64<32, 16384>(pA, pB, acc);
    } else {
        const int e = b - 384;
        const int x = e & 7, r = e >> 3;      // r in [0,16)
        const int s = r & 1, g = r >> 1;      // g in [0,8)
        mg = g * 8 + x; gidx = 3; ngrp = s;
        const unsigned short* pA = Eb + (size_t)mg * 4 * 8192 + bl;
        const unsigned short* pB = wp + WP_V + ngrp * 40960 + bl;
        gemm_m64<16, 8192>(pA, pB, acc);
    }

    unsigned short* Pg = Pb + (size_t)gidx * 655360;
#pragma unroll
    for (int mt = 0; mt < 4; ++mt)
#pragma unroll
        for (int t = 0; t < 5; ++t) {
            const int col = ngrp * 80 + t * 16 + l15;
#pragma unroll
            for (int i = 0; i < 4; ++i)
                Pg[(size_t)(mg * 64 + mt * 16 + quad * 4 + i) * PR + col] =
                    (col < HID) ? f2bf(acc[mt][t][i]) : (unsigned short)0;
        }
}

// ---------------------------------------------------------------------------
// Attn tail: one wave per 16 tokens, barrier-free. h1 = relu(P0 + ba1) as
// A-frags from bf16 P0; layer2 MFMA vs packed Wa2; layer3 shuffle-reduce.
// ---------------------------------------------------------------------------
__global__ __launch_bounds__(64) void attn_tail_kernel(
    const unsigned short* __restrict__ P0, const float* __restrict__ ba1,
    const unsigned short* __restrict__ wp, const float* __restrict__ ba2,
    const float* __restrict__ Wa3, const float* __restrict__ ba3,
    float* __restrict__ attns)
{
    const int t0 = blockIdx.x * 16;
    const int lane = threadIdx.x, l15 = lane & 15, quad = lane >> 4;

    f32x4 acc[10];
#pragma unroll
    for (int nt = 0; nt < 10; ++nt)
#pragma unroll
        for (int i = 0; i < 4; ++i) acc[nt][i] = 0.f;

    const unsigned short* prow = P0 + (size_t)(t0 + l15) * PR;
    const unsigned short* bb = wp + WP_A2 + l15 * KP2 + quad * 8;

#pragma unroll
    for (int c = 0; c < 5; ++c) {
        const int k0 = c * 32;
        const int kk = k0 + quad * 8;
        bf16x8 raw = *(const bf16x8*)(prow + kk);
        bf16x8 af;
#pragma unroll
        for (int j = 0; j < 8; ++j) {
            const float b = (kk + j < HID) ? ba1[kk + j] : 0.f;
            af[j] = (short)f2bf(fmaxf(bf2f(raw[j]) + b, 0.f));
        }
#pragma unroll
        for (int nt = 0; nt < 10; ++nt) {
            bf16x8 bf = *(const bf16x8*)(bb + nt * 16 * KP2 + k0);
            acc[nt] = __builtin_amdgcn_mfma_f32_16x16x32_bf16(af, bf, acc[nt], 0, 0, 0);
        }
    }

    float sc[4] = {0.f, 0.f, 0.f, 0.f};
#pragma unroll
    for (int nt = 0; nt < 10; ++nt) {
        const int col = nt * 16 + l15;
        const float w3 = (col < HID) ? Wa3[col] : 0.f;
        const float b2 = (col < HID) ? ba2[col] : 0.f;
#pragma unroll
        for (int i = 0; i < 4; ++i)
            sc[i] = fmaf(fmaxf(acc[nt][i] + b2, 0.f), w3, sc[i]);
    }
#pragma unroll
    for (int off = 8; off >= 1; off >>= 1)
#pragma unroll
        for (int i = 0; i < 4; ++i) sc[i] += __shfl_down(sc[i], off, 16);
    if (l15 == 0) {
        const float b3 = ba3[0];
#pragma unroll
        for (int i = 0; i < 4; ++i) attns[t0 + quad * 4 + i] = sc[i] + b3;
    }
}

// ---------------------------------------------------------------------------
// Span kernel: 32 spans/block, grid 1024, with in-block width rank-sort.
// ---------------------------------------------------------------------------
__global__ __launch_bounds__(256) void span_kernel(
    const unsigned short* __restrict__ Pb, const float* __restrict__ attns,
    const unsigned short* __restrict__ wp,
    const int* __restrict__ span_starts, const int* __restrict__ span_widths,
    const float* __restrict__ bs1, const float* __restrict__ bs2,
    const float* __restrict__ Ws3, const float* __restrict__ bs3,
    float* __restrict__ out)
{
    __shared__ unsigned short sHb[32][168];
    __shared__ float s_wgt[32][W_MAX];
    __shared__ int s_st[32], s_wd[32], s_bin[32], s_oid[32], s_wdr[32];
    __shared__ float sPart[4][32];
    __shared__ float sb1[KP2];

    const int tid = threadIdx.x;
    const int n0s = blockIdx.x * 32;

    if (tid < KP2) sb1[tid] = (tid < HID) ? bs1[tid] : 0.f;
    int st = 0, wd = 0;
    if (tid < 32) {
        st = span_starts[n0s + tid];
        wd = span_widths[n0s + tid];
        s_wdr[tid] = wd;
    }
    __syncthreads();
    if (tid < 32) {
        int rank = 0;
#pragma unroll
        for (int j = 0; j < 32; ++j) {
            const int wj = s_wdr[j];
            rank += (wj < wd) || (wj == wd && j < tid);
        }
        s_st[rank] = st; s_wd[rank] = wd; s_oid[rank] = tid;
        s_bin[rank] = (wd >= 1) + (wd >= 2) + (wd >= 3) + (wd >= 4) +
                      (wd >= 8) + (wd >= 16) + (wd >= 32) + (wd >= 64);
        float lg[W_MAX];
        float m = -1e30f;
#pragma unroll
        for (int w = 0; w < W_MAX; ++w)
            if (w < wd) { float a = attns[st + w]; lg[w] = a; m = fmaxf(m, a); }
        float sum = 0.f;
#pragma unroll
        for (int w = 0; w < W_MAX; ++w) {
            float e = (w < wd) ? __expf(lg[w] - m) : 0.f;
            lg[w] = e; sum += e;
        }
        float inv = 1.f / sum;
#pragma unroll
        for (int w = 0; w < W_MAX; ++w) s_wgt[rank][w] = lg[w] * inv;
    }
    __syncthreads();

    // gather-combine: 8 lanes/span, bf16x8 chunks (spans width-sorted)
    {
        const unsigned short* P1b = Pb + PB_P1;
        const unsigned short* P2b = Pb + PB_P2;
        const unsigned short* P3b = Pb + PB_P3;
        const unsigned short* WEb = wp + WP_WE1;
        const int s = tid >> 3, jl = tid & 7;
        const int sst = s_st[s], swd = s_wd[s];
        const size_t rs = (size_t)sst * PR;
        const size_t re = (size_t)(sst + swd - 1) * PR;
        const size_t rb = (size_t)s_bin[s] * PR;
        for (int c = jl; c < 20; c += 8) {
            const int j = c * 8;
            bf16x8 u1 = *(const bf16x8*)(P1b + rs + j);
            bf16x8 u2 = *(const bf16x8*)(P2b + re + j);
            bf16x8 uw = *(const bf16x8*)(WEb + rb + j);
            float acc[8];
#pragma unroll
            for (int i = 0; i < 8; ++i)
                acc[i] = bf2f(u1[i]) + bf2f(u2[i]) + bf2f(uw[i]) + sb1[j + i];
#pragma unroll
            for (int w = 0; w < W_MAX; ++w) {
                if (w < swd) {
                    float wt = s_wgt[s][w];
                    bf16x8 uv = *(const bf16x8*)(P3b + rs + (size_t)w * PR + j);
#pragma unroll
                    for (int i = 0; i < 8; ++i)
                        acc[i] = fmaf(wt, bf2f(uv[i]), acc[i]);
                }
            }
            bf16x8 pk;
#pragma unroll
            for (int i = 0; i < 8; ++i) pk[i] = (short)f2bf(fmaxf(acc[i], 0.f));
            *(bf16x8*)&sHb[s][j] = pk;
        }
    }
    __syncthreads();

    // layer2 MFMA: M=32 (2 m-tiles), N=160 (tiles 3,3,2,2 over waves)
    const int wv = tid >> 6, lane = tid & 63, l15 = lane & 15, quad = lane >> 4;
    const int nb = (wv < 2) ? wv * 3 : 6 + (wv - 2) * 2;
    const int cnt = (wv < 2) ? 3 : 2;

    f32x4 a2[2][3];
#pragma unroll
    for (int mt = 0; mt < 2; ++mt)
#pragma unroll
        for (int t = 0; t < 3; ++t)
#pragma unroll
            for (int i = 0; i < 4; ++i) a2[mt][t][i] = 0.f;

#pragma unroll
    for (int c = 0; c < 5; ++c) {
        int k0 = c * 32;
        bf16x8 af0 = *(const bf16x8*)&sHb[l15][k0 + quad * 8];
        bf16x8 af1 = *(const bf16x8*)&sHb[16 + l15][k0 + quad * 8];
#pragma unroll
        for (int t = 0; t < 3; ++t) {
            if (t < cnt) {
                bf16x8 b = *(const bf16x8*)(wp + WP_S2 +
                            (size_t)((nb + t) * 16 + l15) * KP2 + k0 + quad * 8);
                a2[0][t] = __builtin_amdgcn_mfma_f32_16x16x32_bf16(af0, b, a2[0][t], 0, 0, 0);
                a2[1][t] = __builtin_amdgcn_mfma_f32_16x16x32_bf16(af1, b, a2[1][t], 0, 0, 0);
            }
        }
    }

    float sc[2][4];
#pragma unroll
    for (int mt = 0; mt < 2; ++mt)
#pragma unroll
        for (int i = 0; i < 4; ++i) sc[mt][i] = 0.f;
#pragma unroll
    for (int t = 0; t < 3; ++t) {
        if (t < cnt) {
            int col = (nb + t) * 16 + l15;
            float w3 = (col < HID) ? Ws3[col] : 0.f;
            float b2 = (col < HID) ? bs2[col] : 0.f;
#pragma unroll
            for (int mt = 0; mt < 2; ++mt)
#pragma unroll
                for (int i = 0; i < 4; ++i)
                    sc[mt][i] = fmaf(fmaxf(a2[mt][t][i] + b2, 0.f), w3, sc[mt][i]);
        }
    }
#pragma unroll
    for (int off = 8; off >= 1; off >>= 1)
#pragma unroll
        for (int mt = 0; mt < 2; ++mt)
#pragma unroll
            for (int i = 0; i < 4; ++i)
                sc[mt][i] += __shfl_down(sc[mt][i], off, 16);
    if (l15 == 0) {
#pragma unroll
        for (int mt = 0; mt < 2; ++mt)
#pragma unroll
            for (int i = 0; i < 4; ++i)
                sPart[wv][mt * 16 + quad * 4 + i] = sc[mt][i];
    }
    __syncthreads();
    if (tid < 32)
        out[n0s + s_oid[tid]] = sPart[0][tid] + sPart[1][tid] + sPart[2][tid] +
                                sPart[3][tid] + bs3[0];
}

// ---------------------------------------------------------------------------
extern "C" void kernel_launch(void* const* d_in, const int* in_sizes, int n_in,
                              void* d_out, int out_size, void* d_ws, size_t ws_size,
                              hipStream_t stream)
{
    const float* states      = (const float*)d_in[0];
    const float* embeds      = (const float*)d_in[1];
    const int*   span_starts = (const int*)d_in[2];
    const int*   span_widths = (const int*)d_in[3];
    const float* Wa1 = (const float*)d_in[4];
    const float* ba1 = (const float*)d_in[5];
    const float* Wa2 = (const float*)d_in[6];
    const float* ba2 = (const float*)d_in[7];
    const float* Wa3 = (const float*)d_in[8];
    const float* ba3 = (const float*)d_in[9];
    const float* width_emb = (const float*)d_in[10];
    const float* Ws1 = (const float*)d_in[11];
    const float* bs1 = (const float*)d_in[12];
    const float* Ws2 = (const float*)d_in[13];
    const float* bs2 = (const float*)d_in[14];
    const float* Ws3 = (const float*)d_in[15];
    const float* bs3 = (const float*)d_in[16];
    float* out = (float*)d_out;

    float* ws    = (float*)d_ws;
    float* attns = ws + WS_ATTNS;
    unsigned short* Pb    = (unsigned short*)(ws + WS_PB);
    unsigned short* wpack = (unsigned short*)(ws + WS_WPACK);
    unsigned short* Sb    = (unsigned short*)(ws + WS_SB);
    unsigned short* Eb    = (unsigned short*)(ws + WS_EB);

    hipLaunchKernelGGL(prepack_kernel, dim3((PK_ITEMS + 255) / 256), dim3(256), 0, stream,
                       states, embeds, Wa1, Ws1, Wa2, Ws2, width_emb,
                       wpack, Sb, Eb);
    hipLaunchKernelGGL(token_kernel, dim3(512), dim3(64), 0, stream,
                       Sb, Eb, wpack, Pb);
    hipLaunchKernelGGL(attn_tail_kernel, dim3(T_TOK / 16), dim3(64), 0, stream,
                       Pb + PB_P0, ba1, wpack, ba2, Wa3, ba3, attns);
    hipLaunchKernelGGL(span_kernel, dim3(N_SPAN / 32), dim3(256), 0, stream,
                       Pb, attns, wpack, span_starts, span_widths,
                       bs1, bs2, Ws3, bs3, out);
}

// Round 6
// 153.652 us; speedup vs baseline: 4.5168x; 1.0312x over previous
//
#include <hip/hip_runtime.h>
#include <math.h>

#define T_TOK 4096
#define A_DIM 1024
#define E_DIM 512
#define N_SPAN 32768
#define W_MAX 10
#define HID 150
#define FD 20

#define PR  160             // P row stride (bf16 elems); cols 150..159 zero
#define KP2 160             // padded K/N for the 150x150 layers

// ---- workspace layout (float offsets) ----
#define WS_ATTNS 0
#define WS_PB    4096
#define WS_WPACK 1314816
#define WS_SB    1627856
#define WS_EB    3725008
// Pb ushort offsets (P0 slot unused: attn fused in token)
#define PB_P0 0
#define PB_P1 655360
#define PB_P2 1310720
#define PB_P3 1966080
// wpack ushort offsets
//   ST: [3 gidx][2 ngrp][32 c][2560]  (chunk-contiguous, XOR-swizzled)
//   V : [2 ngrp][16 c][2560]
//   A2/S2: [160 n][160 k] n-major;  WE1: [9][160]
#define WP_ST  0
#define WP_V   491520
#define WP_A2  573440
#define WP_S2  599040
#define WP_WE1 624640
#define WP_TOTAL 626080
#define SB_PIECES 524288     // 4096*1024/8
#define EB_PIECES 262144     // 4096*512/8
#define PK_ITEMS (WP_TOTAL + SB_PIECES + EB_PIECES)

typedef short  bf16x8 __attribute__((ext_vector_type(8)));
typedef float  f32x4  __attribute__((ext_vector_type(4)));

__device__ __forceinline__ float4 ld4(const float* p) { return *(const float4*)p; }

__device__ __forceinline__ unsigned short f2bf(float f) {
    unsigned u = __float_as_uint(f);
    unsigned r = u + 0x7fffu + ((u >> 16) & 1u);   // RNE
    return (unsigned short)(r >> 16);
}
__device__ __forceinline__ float bf2f(short s) {
    return __uint_as_float(((unsigned)(unsigned short)s) << 16);
}
__device__ __forceinline__ bf16x8 cvt_frag(const float* p) {
    float4 u = ld4(p), v = ld4(p + 4);
    bf16x8 f;
    f[0] = (short)f2bf(u.x); f[1] = (short)f2bf(u.y);
    f[2] = (short)f2bf(u.z); f[3] = (short)f2bf(u.w);
    f[4] = (short)f2bf(v.x); f[5] = (short)f2bf(v.y);
    f[6] = (short)f2bf(v.z); f[7] = (short)f2bf(v.w);
    return f;
}

// ---------------------------------------------------------------------------
// Prepack (dst-linear, coalesced writes): weights + Sb/Eb bf16 staging.
// ---------------------------------------------------------------------------
__global__ __launch_bounds__(256) void prepack_kernel(
    const float* __restrict__ states, const float* __restrict__ embeds,
    const float* __restrict__ Wa1, const float* __restrict__ Ws1,
    const float* __restrict__ Wa2, const float* __restrict__ Ws2,
    const float* __restrict__ width_emb,
    unsigned short* __restrict__ wp, unsigned short* __restrict__ Sb,
    unsigned short* __restrict__ Eb)
{
    int idx = blockIdx.x * 256 + threadIdx.x;
    if (idx >= PK_ITEMS) return;
    if (idx < WP_TOTAL) {
        float v = 0.f;
        if (idx < WP_V) {                               // ST: 3 x 2 x 32 x 2560
            int gidx = idx / 163840, r = idx % 163840;
            int ngrp = r / 81920, r2 = r % 81920;
            int c = r2 / 2560, d = r2 % 2560;
            int n = d >> 5, qsw = (d >> 3) & 3, off = d & 7;
            int q = qsw ^ ((n >> 1) & 3);
            int k = c * 32 + q * 8 + off;
            int gn = ngrp * 80 + n;
            const float* W = (gidx == 0) ? Wa1 : Ws1 + (size_t)(gidx - 1) * 1024 * HID;
            if (gn < HID) v = W[(size_t)k * HID + gn];
        } else if (idx < WP_A2) {                       // V: 2 x 16 x 2560
            int r = idx - WP_V;
            int ngrp = r / 40960, r2 = r % 40960;
            int c = r2 / 2560, d = r2 % 2560;
            int n = d >> 5, qsw = (d >> 3) & 3, off = d & 7;
            int q = qsw ^ ((n >> 1) & 3);
            int k = c * 32 + q * 8 + off;
            int gn = ngrp * 80 + n;
            if (gn < HID) v = Ws1[(size_t)(2048 + k) * HID + gn];
        } else if (idx < WP_S2) {                       // Wa2 [n][160]
            int e = idx - WP_A2;
            int n = e / KP2, k = e % KP2;
            if (n < HID && k < HID) v = Wa2[(size_t)k * HID + n];
        } else if (idx < WP_WE1) {                      // Ws2 [n][160]
            int e = idx - WP_S2;
            int n = e / KP2, k = e % KP2;
            if (n < HID && k < HID) v = Ws2[(size_t)k * HID + n];
        } else {                                        // WE1 [9][160]
            int e = idx - WP_WE1;
            int b = e / KP2, n = e % KP2;
            if (n < HID)
                for (int k = 0; k < FD; ++k)
                    v = fmaf(width_emb[b * FD + k], Ws1[(size_t)(2560 + k) * HID + n], v);
        }
        wp[idx] = f2bf(v);
    } else if (idx < WP_TOTAL + SB_PIECES) {            // Sb piece (8 elems)
        int p = idx - WP_TOTAL;
        int mb = p >> 11, r = p & 2047;                 // 2048 pieces per 16-row tile
        int c = r >> 6, d8 = r & 63;
        int m = d8 >> 2, qsw = d8 & 3;
        int q = qsw ^ ((m >> 1) & 3);
        const float* src = states + (size_t)(mb * 16 + m) * A_DIM + c * 32 + q * 8;
        *(bf16x8*)(Sb + (size_t)p * 8) = cvt_frag(src);
    } else {                                            // Eb piece
        int p = idx - WP_TOTAL - SB_PIECES;
        int mb = p >> 10, r = p & 1023;                 // 1024 pieces per tile
        int c = r >> 6, d8 = r & 63;
        int m = d8 >> 2, qsw = d8 & 3;
        int q = qsw ^ ((m >> 1) & 3);
        const float* src = embeds + (size_t)(mb * 16 + m) * E_DIM + c * 32 + q * 8;
        *(bf16x8*)(Eb + (size_t)p * 8) = cvt_frag(src);
    }
}

// ---------------------------------------------------------------------------
// All-register M=32 GEMM strip (R4-verified gemm_reg): one wave owns 2
// m-tiles x 80 cols x full K. Per chunk: 7 coalesced 16B/lane register
// loads (2 A + 5 B), 10 MFMA. Depth-2 double-buffered register pipeline,
// compiler-scheduled waitcnt; B frags amortized over both m-tiles.
// ---------------------------------------------------------------------------
template<int NCH>
__device__ __forceinline__ void gemm_reg(
    const unsigned short* __restrict__ pA0, const unsigned short* __restrict__ pA1,
    const unsigned short* __restrict__ pB, f32x4 (&acc)[2][5])
{
    bf16x8 a0[2], a1[2], bb[2][5];
#define LDC(c, s) { \
        a0[s] = *(const bf16x8*)(pA0 + (size_t)(c) * 512); \
        a1[s] = *(const bf16x8*)(pA1 + (size_t)(c) * 512); \
        _Pragma("unroll") \
        for (int t = 0; t < 5; ++t) \
            bb[s][t] = *(const bf16x8*)(pB + (size_t)(c) * 2560 + t * 512); }
    LDC(0, 0);
#pragma unroll
    for (int c = 0; c < NCH; ++c) {
        const int s = c & 1;
        if (c + 1 < NCH) LDC(c + 1, s ^ 1);
#pragma unroll
        for (int t = 0; t < 5; ++t) {
            acc[0][t] = __builtin_amdgcn_mfma_f32_16x16x32_bf16(a0[s], bb[s][t], acc[0][t], 0, 0, 0);
            acc[1][t] = __builtin_amdgcn_mfma_f32_16x16x32_bf16(a1[s], bb[s][t], acc[1][t], 0, 0, 0);
        }
    }
#undef LDC
}

// ---------------------------------------------------------------------------
// Token kernel: 512 blocks x 128 thr (2 INDEPENDENT waves; wave = ngrp).
// Block covers 32 rows x one weight panel; all-register GEMM (no LDS/dma).
//   b <  384 : t=2b+wv, mb32=t/6, gidx=(t%6)>>1 (uniform/block), ngrp=wv
//              gidx==0: fused attention tail in-block (h1 -> LDS ->
//              per-wave 16-token layer2/3; no P0 round trip)
//   b >= 384 : mb32=b-384, embeds x V -> P3 (K=512)
// ---------------------------------------------------------------------------
__global__ __launch_bounds__(128) void token_kernel(
    const unsigned short* __restrict__ Sb, const unsigned short* __restrict__ Eb,
    const unsigned short* __restrict__ wp, unsigned short* __restrict__ Pb,
    const float* __restrict__ ba1, const float* __restrict__ ba2,
    const float* __restrict__ Wa3, const float* __restrict__ ba3,
    float* __restrict__ attns)
{
    __shared__ __align__(16) unsigned short sHb[32][168];   // 10.5 KB

    const int wv = threadIdx.x >> 6;
    const int lane = threadIdx.x & 63, l15 = lane & 15, quad = lane >> 4;
    const int bl = l15 * 32 + ((quad ^ ((l15 >> 1) & 3)) * 8);
    const int b = blockIdx.x;
    const int ngrp = wv;

    f32x4 acc[2][5];
#pragma unroll
    for (int mt = 0; mt < 2; ++mt)
#pragma unroll
        for (int t = 0; t < 5; ++t)
#pragma unroll
            for (int i = 0; i < 4; ++i) acc[mt][t][i] = 0.f;

    int mb32, gidx;
    if (b < 384) {
        const int t = b * 2 + wv;
        mb32 = t / 6;
        gidx = (t % 6) >> 1;             // uniform across the block's 2 waves
        const unsigned short* pA0 = Sb + (size_t)(mb32 * 2) * 16384 + bl;
        const unsigned short* pA1 = pA0 + 16384;
        const unsigned short* pB  = wp + WP_ST + gidx * 163840 + ngrp * 81920 + bl;
        gemm_reg<32>(pA0, pA1, pB, acc);
    } else {
        mb32 = b - 384;
        gidx = 3;                        // V -> P3
        const unsigned short* pA0 = Eb + (size_t)(mb32 * 2) * 8192 + bl;
        const unsigned short* pA1 = pA0 + 8192;
        const unsigned short* pB  = wp + WP_V + ngrp * 40960 + bl;
        gemm_reg<16>(pA0, pA1, pB, acc);
    }

    if (gidx == 0) {
        // ---- fused attention tail for tokens mb32*32 .. +31 ----
        // (1) h1 = relu(acc + ba1) -> bf16 LDS tile [32 rows][160 cols]
#pragma unroll
        for (int mt = 0; mt < 2; ++mt)
#pragma unroll
            for (int t = 0; t < 5; ++t) {
                const int col = ngrp * 80 + t * 16 + l15;
                const float b1 = (col < HID) ? ba1[col] : 0.f;
#pragma unroll
                for (int i = 0; i < 4; ++i)
                    sHb[mt * 16 + quad * 4 + i][col] =
                        (col < HID) ? f2bf(fmaxf(acc[mt][t][i] + b1, 0.f))
                                    : (unsigned short)0;
            }
        __syncthreads();
        // (2) per-wave: 16 tokens (rows wv*16..+15), layer2 MFMA + layer3
        const int t0 = mb32 * 32 + wv * 16;
        f32x4 a2[10];
#pragma unroll
        for (int nt = 0; nt < 10; ++nt)
#pragma unroll
            for (int i = 0; i < 4; ++i) a2[nt][i] = 0.f;

        const unsigned short* prow = &sHb[wv * 16 + l15][0];
        const unsigned short* bb = wp + WP_A2 + l15 * KP2 + quad * 8;
#pragma unroll
        for (int c = 0; c < 5; ++c) {
            const int k0 = c * 32;
            bf16x8 af = *(const bf16x8*)(prow + k0 + quad * 8);
#pragma unroll
            for (int nt = 0; nt < 10; ++nt) {
                bf16x8 bf = *(const bf16x8*)(bb + nt * 16 * KP2 + k0);
                a2[nt] = __builtin_amdgcn_mfma_f32_16x16x32_bf16(af, bf, a2[nt], 0, 0, 0);
            }
        }
        float sc[4] = {0.f, 0.f, 0.f, 0.f};
#pragma unroll
        for (int nt = 0; nt < 10; ++nt) {
            const int col = nt * 16 + l15;
            const float w3 = (col < HID) ? Wa3[col] : 0.f;
            const float b2 = (col < HID) ? ba2[col] : 0.f;
#pragma unroll
            for (int i = 0; i < 4; ++i)
                sc[i] = fmaf(fmaxf(a2[nt][i] + b2, 0.f), w3, sc[i]);
        }
#pragma unroll
        for (int off = 8; off >= 1; off >>= 1)
#pragma unroll
            for (int i = 0; i < 4; ++i) sc[i] += __shfl_down(sc[i], off, 16);
        if (l15 == 0) {
            const float b3 = ba3[0];
#pragma unroll
            for (int i = 0; i < 4; ++i) attns[t0 + quad * 4 + i] = sc[i] + b3;
        }
    } else {
        unsigned short* Pg = Pb + (size_t)gidx * 655360;
#pragma unroll
        for (int mt = 0; mt < 2; ++mt)
#pragma unroll
            for (int t = 0; t < 5; ++t) {
                const int col = ngrp * 80 + t * 16 + l15;
#pragma unroll
                for (int i = 0; i < 4; ++i)
                    Pg[(size_t)(mb32 * 32 + mt * 16 + quad * 4 + i) * PR + col] =
                        (col < HID) ? f2bf(acc[mt][t][i]) : (unsigned short)0;
            }
    }
}

// ---------------------------------------------------------------------------
// Span kernel: 32 spans/block, grid 1024, with in-block width rank-sort.
// ---------------------------------------------------------------------------
__global__ __launch_bounds__(256) void span_kernel(
    const unsigned short* __restrict__ Pb, const float* __restrict__ attns,
    const unsigned short* __restrict__ wp,
    const int* __restrict__ span_starts, const int* __restrict__ span_widths,
    const float* __restrict__ bs1, const float* __restrict__ bs2,
    const float* __restrict__ Ws3, const float* __restrict__ bs3,
    float* __restrict__ out)
{
    __shared__ unsigned short sHb[32][168];
    __shared__ float s_wgt[32][W_MAX];
    __shared__ int s_st[32], s_wd[32], s_bin[32], s_oid[32], s_wdr[32];
    __shared__ float sPart[4][32];
    __shared__ float sb1[KP2];

    const int tid = threadIdx.x;
    const int n0s = blockIdx.x * 32;

    if (tid < KP2) sb1[tid] = (tid < HID) ? bs1[tid] : 0.f;
    int st = 0, wd = 0;
    if (tid < 32) {
        st = span_starts[n0s + tid];
        wd = span_widths[n0s + tid];
        s_wdr[tid] = wd;
    }
    __syncthreads();
    if (tid < 32) {
        int rank = 0;
#pragma unroll
        for (int j = 0; j < 32; ++j) {
            const int wj = s_wdr[j];
            rank += (wj < wd) || (wj == wd && j < tid);
        }
        s_st[rank] = st; s_wd[rank] = wd; s_oid[rank] = tid;
        s_bin[rank] = (wd >= 1) + (wd >= 2) + (wd >= 3) + (wd >= 4) +
                      (wd >= 8) + (wd >= 16) + (wd >= 32) + (wd >= 64);
        float lg[W_MAX];
        float m = -1e30f;
#pragma unroll
        for (int w = 0; w < W_MAX; ++w)
            if (w < wd) { float a = attns[st + w]; lg[w] = a; m = fmaxf(m, a); }
        float sum = 0.f;
#pragma unroll
        for (int w = 0; w < W_MAX; ++w) {
            float e = (w < wd) ? __expf(lg[w] - m) : 0.f;
            lg[w] = e; sum += e;
        }
        float inv = 1.f / sum;
#pragma unroll
        for (int w = 0; w < W_MAX; ++w) s_wgt[rank][w] = lg[w] * inv;
    }
    __syncthreads();

    // gather-combine: 8 lanes/span, bf16x8 chunks (spans width-sorted)
    {
        const unsigned short* P1b = Pb + PB_P1;
        const unsigned short* P2b = Pb + PB_P2;
        const unsigned short* P3b = Pb + PB_P3;
        const unsigned short* WEb = wp + WP_WE1;
        const int s = tid >> 3, jl = tid & 7;
        const int sst = s_st[s], swd = s_wd[s];
        const size_t rs = (size_t)sst * PR;
        const size_t re = (size_t)(sst + swd - 1) * PR;
        const size_t rb = (size_t)s_bin[s] * PR;
        for (int c = jl; c < 20; c += 8) {
            const int j = c * 8;
            bf16x8 u1 = *(const bf16x8*)(P1b + rs + j);
            bf16x8 u2 = *(const bf16x8*)(P2b + re + j);
            bf16x8 uw = *(const bf16x8*)(WEb + rb + j);
            float acc[8];
#pragma unroll
            for (int i = 0; i < 8; ++i)
                acc[i] = bf2f(u1[i]) + bf2f(u2[i]) + bf2f(uw[i]) + sb1[j + i];
#pragma unroll
            for (int w = 0; w < W_MAX; ++w) {
                if (w < swd) {
                    float wt = s_wgt[s][w];
                    bf16x8 uv = *(const bf16x8*)(P3b + rs + (size_t)w * PR + j);
#pragma unroll
                    for (int i = 0; i < 8; ++i)
                        acc[i] = fmaf(wt, bf2f(uv[i]), acc[i]);
                }
            }
            bf16x8 pk;
#pragma unroll
            for (int i = 0; i < 8; ++i) pk[i] = (short)f2bf(fmaxf(acc[i], 0.f));
            *(bf16x8*)&sHb[s][j] = pk;
        }
    }
    __syncthreads();

    // layer2 MFMA: M=32 (2 m-tiles), N=160 (tiles 3,3,2,2 over waves)
    const int wv = tid >> 6, lane = tid & 63, l15 = lane & 15, quad = lane >> 4;
    const int nb = (wv < 2) ? wv * 3 : 6 + (wv - 2) * 2;
    const int cnt = (wv < 2) ? 3 : 2;

    f32x4 a2[2][3];
#pragma unroll
    for (int mt = 0; mt < 2; ++mt)
#pragma unroll
        for (int t = 0; t < 3; ++t)
#pragma unroll
            for (int i = 0; i < 4; ++i) a2[mt][t][i] = 0.f;

#pragma unroll
    for (int c = 0; c < 5; ++c) {
        int k0 = c * 32;
        bf16x8 af0 = *(const bf16x8*)&sHb[l15][k0 + quad * 8];
        bf16x8 af1 = *(const bf16x8*)&sHb[16 + l15][k0 + quad * 8];
#pragma unroll
        for (int t = 0; t < 3; ++t) {
            if (t < cnt) {
                bf16x8 b = *(const bf16x8*)(wp + WP_S2 +
                            (size_t)((nb + t) * 16 + l15) * KP2 + k0 + quad * 8);
                a2[0][t] = __builtin_amdgcn_mfma_f32_16x16x32_bf16(af0, b, a2[0][t], 0, 0, 0);
                a2[1][t] = __builtin_amdgcn_mfma_f32_16x16x32_bf16(af1, b, a2[1][t], 0, 0, 0);
            }
        }
    }

    float sc[2][4];
#pragma unroll
    for (int mt = 0; mt < 2; ++mt)
#pragma unroll
        for (int i = 0; i < 4; ++i) sc[mt][i] = 0.f;
#pragma unroll
    for (int t = 0; t < 3; ++t) {
        if (t < cnt) {
            int col = (nb + t) * 16 + l15;
            float w3 = (col < HID) ? Ws3[col] : 0.f;
            float b2 = (col < HID) ? bs2[col] : 0.f;
#pragma unroll
            for (int mt = 0; mt < 2; ++mt)
#pragma unroll
                for (int i = 0; i < 4; ++i)
                    sc[mt][i] = fmaf(fmaxf(a2[mt][t][i] + b2, 0.f), w3, sc[mt][i]);
        }
    }
#pragma unroll
    for (int off = 8; off >= 1; off >>= 1)
#pragma unroll
        for (int mt = 0; mt < 2; ++mt)
#pragma unroll
            for (int i = 0; i < 4; ++i)
                sc[mt][i] += __shfl_down(sc[mt][i], off, 16);
    if (l15 == 0) {
#pragma unroll
        for (int mt = 0; mt < 2; ++mt)
#pragma unroll
            for (int i = 0; i < 4; ++i)
                sPart[wv][mt * 16 + quad * 4 + i] = sc[mt][i];
    }
    __syncthreads();
    if (tid < 32)
        out[n0s + s_oid[tid]] = sPart[0][tid] + sPart[1][tid] + sPart[2][tid] +
                                sPart[3][tid] + bs3[0];
}

// ---------------------------------------------------------------------------
extern "C" void kernel_launch(void* const* d_in, const int* in_sizes, int n_in,
                              void* d_out, int out_size, void* d_ws, size_t ws_size,
                              hipStream_t stream)
{
    const float* states      = (const float*)d_in[0];
    const float* embeds      = (const float*)d_in[1];
    const int*   span_starts = (const int*)d_in[2];
    const int*   span_widths = (const int*)d_in[3];
    const float* Wa1 = (const float*)d_in[4];
    const float* ba1 = (const float*)d_in[5];
    const float* Wa2 = (const float*)d_in[6];
    const float* ba2 = (const float*)d_in[7];
    const float* Wa3 = (const float*)d_in[8];
    const float* ba3 = (const float*)d_in[9];
    const float* width_emb = (const float*)d_in[10];
    const float* Ws1 = (const float*)d_in[11];
    const float* bs1 = (const float*)d_in[12];
    const float* Ws2 = (const float*)d_in[13];
    const float* bs2 = (const float*)d_in[14];
    const float* Ws3 = (const float*)d_in[15];
    const float* bs3 = (const float*)d_in[16];
    float* out = (float*)d_out;

    float* ws    = (float*)d_ws;
    float* attns = ws + WS_ATTNS;
    unsigned short* Pb    = (unsigned short*)(ws + WS_PB);
    unsigned short* wpack = (unsigned short*)(ws + WS_WPACK);
    unsigned short* Sb    = (unsigned short*)(ws + WS_SB);
    unsigned short* Eb    = (unsigned short*)(ws + WS_EB);

    hipLaunchKernelGGL(prepack_kernel, dim3((PK_ITEMS + 255) / 256), dim3(256), 0, stream,
                       states, embeds, Wa1, Ws1, Wa2, Ws2, width_emb,
                       wpack, Sb, Eb);
    hipLaunchKernelGGL(token_kernel, dim3(512), dim3(128), 0, stream,
                       Sb, Eb, wpack, Pb, ba1, ba2, Wa3, ba3, attns);
    hipLaunchKernelGGL(span_kernel, dim3(N_SPAN / 32), dim3(256), 0, stream,
                       Pb, attns, wpack, span_starts, span_widths,
                       bs1, bs2, Ws3, bs3, out);
}

// Round 7
// 146.430 us; speedup vs baseline: 4.7395x; 1.0493x over previous
//
#include <hip/hip_runtime.h>
#include <math.h>

#define T_TOK 4096
#define A_DIM 1024
#define E_DIM 512
#define N_SPAN 32768
#define W_MAX 10
#define HID 150
#define FD 20

#define PR  160             // P row stride (bf16 elems); cols 150..159 zero
#define KP2 160             // padded K/N for the 150x150 layers

// ---- workspace layout (float offsets) ----
#define WS_ATTNS 0
#define WS_PB    4096
#define WS_WPACK 1314816
#define WS_SB    1627856
#define WS_EB    3725008
// Pb ushort offsets (P0 slot unused: attn fused in token)
#define PB_P0 0
#define PB_P1 655360
#define PB_P2 1310720
#define PB_P3 1966080
// wpack ushort offsets
//   ST: [3 gidx][2 ngrp][32 c][2560]  (chunk-contiguous, XOR-swizzled)
//   V : [2 ngrp][16 c][2560]
//   A2/S2: [160 n][160 k] n-major;  WE1: [9][160]
#define WP_ST  0
#define WP_V   491520
#define WP_A2  573440
#define WP_S2  599040
#define WP_WE1 624640
#define WP_TOTAL 626080
#define SB_PIECES 524288     // 4096*1024/8
#define EB_PIECES 262144     // 4096*512/8
#define PK_ITEMS (WP_TOTAL + SB_PIECES + EB_PIECES)

typedef short  bf16x8 __attribute__((ext_vector_type(8)));
typedef float  f32x4  __attribute__((ext_vector_type(4)));

__device__ __forceinline__ float4 ld4(const float* p) { return *(const float4*)p; }

__device__ __forceinline__ unsigned short f2bf(float f) {
    unsigned u = __float_as_uint(f);
    unsigned r = u + 0x7fffu + ((u >> 16) & 1u);   // RNE
    return (unsigned short)(r >> 16);
}
__device__ __forceinline__ float bf2f(short s) {
    return __uint_as_float(((unsigned)(unsigned short)s) << 16);
}
__device__ __forceinline__ bf16x8 cvt_frag(const float* p) {
    float4 u = ld4(p), v = ld4(p + 4);
    bf16x8 f;
    f[0] = (short)f2bf(u.x); f[1] = (short)f2bf(u.y);
    f[2] = (short)f2bf(u.z); f[3] = (short)f2bf(u.w);
    f[4] = (short)f2bf(v.x); f[5] = (short)f2bf(v.y);
    f[6] = (short)f2bf(v.z); f[7] = (short)f2bf(v.w);
    return f;
}

// async global->LDS, 16 B/lane; LDS dst = wave-uniform base + lane*16
typedef const __attribute__((address_space(1))) unsigned int as1_u32;
typedef __attribute__((address_space(3))) unsigned int as3_u32;
__device__ __forceinline__ void dma16(const void* g, void* l) {
    __builtin_amdgcn_global_load_lds((as1_u32*)g, (as3_u32*)l, 16, 0, 0);
}
template<int N> __device__ __forceinline__ void waitv() {
    asm volatile("s_waitcnt vmcnt(%0)" :: "n"(N) : "memory");
}

// ---------------------------------------------------------------------------
// Prepack (dst-linear, coalesced writes): weights + Sb/Eb bf16 staging.
// ---------------------------------------------------------------------------
__global__ __launch_bounds__(256) void prepack_kernel(
    const float* __restrict__ states, const float* __restrict__ embeds,
    const float* __restrict__ Wa1, const float* __restrict__ Ws1,
    const float* __restrict__ Wa2, const float* __restrict__ Ws2,
    const float* __restrict__ width_emb,
    unsigned short* __restrict__ wp, unsigned short* __restrict__ Sb,
    unsigned short* __restrict__ Eb)
{
    int idx = blockIdx.x * 256 + threadIdx.x;
    if (idx >= PK_ITEMS) return;
    if (idx < WP_TOTAL) {
        float v = 0.f;
        if (idx < WP_V) {                               // ST: 3 x 2 x 32 x 2560
            int gidx = idx / 163840, r = idx % 163840;
            int ngrp = r / 81920, r2 = r % 81920;
            int c = r2 / 2560, d = r2 % 2560;
            int n = d >> 5, qsw = (d >> 3) & 3, off = d & 7;
            int q = qsw ^ ((n >> 1) & 3);
            int k = c * 32 + q * 8 + off;
            int gn = ngrp * 80 + n;
            const float* W = (gidx == 0) ? Wa1 : Ws1 + (size_t)(gidx - 1) * 1024 * HID;
            if (gn < HID) v = W[(size_t)k * HID + gn];
        } else if (idx < WP_A2) {                       // V: 2 x 16 x 2560
            int r = idx - WP_V;
            int ngrp = r / 40960, r2 = r % 40960;
            int c = r2 / 2560, d = r2 % 2560;
            int n = d >> 5, qsw = (d >> 3) & 3, off = d & 7;
            int q = qsw ^ ((n >> 1) & 3);
            int k = c * 32 + q * 8 + off;
            int gn = ngrp * 80 + n;
            if (gn < HID) v = Ws1[(size_t)(2048 + k) * HID + gn];
        } else if (idx < WP_S2) {                       // Wa2 [n][160]
            int e = idx - WP_A2;
            int n = e / KP2, k = e % KP2;
            if (n < HID && k < HID) v = Wa2[(size_t)k * HID + n];
        } else if (idx < WP_WE1) {                      // Ws2 [n][160]
            int e = idx - WP_S2;
            int n = e / KP2, k = e % KP2;
            if (n < HID && k < HID) v = Ws2[(size_t)k * HID + n];
        } else {                                        // WE1 [9][160]
            int e = idx - WP_WE1;
            int b = e / KP2, n = e % KP2;
            if (n < HID)
                for (int k = 0; k < FD; ++k)
                    v = fmaf(width_emb[b * FD + k], Ws1[(size_t)(2560 + k) * HID + n], v);
        }
        wp[idx] = f2bf(v);
    } else if (idx < WP_TOTAL + SB_PIECES) {            // Sb piece (8 elems)
        int p = idx - WP_TOTAL;
        int mb = p >> 11, r = p & 2047;                 // 2048 pieces per 16-row tile
        int c = r >> 6, d8 = r & 63;
        int m = d8 >> 2, qsw = d8 & 3;
        int q = qsw ^ ((m >> 1) & 3);
        const float* src = states + (size_t)(mb * 16 + m) * A_DIM + c * 32 + q * 8;
        *(bf16x8*)(Sb + (size_t)p * 8) = cvt_frag(src);
    } else {                                            // Eb piece
        int p = idx - WP_TOTAL - SB_PIECES;
        int mb = p >> 10, r = p & 1023;                 // 1024 pieces per tile
        int c = r >> 6, d8 = r & 63;
        int m = d8 >> 2, qsw = d8 & 3;
        int q = qsw ^ ((m >> 1) & 3);
        const float* src = embeds + (size_t)(mb * 16 + m) * E_DIM + c * 32 + q * 8;
        *(bf16x8*)(Eb + (size_t)p * 8) = cvt_frag(src);
    }
}

// ---------------------------------------------------------------------------
// DMA-pipelined M=32 GEMM strip: B triple-buffered depth-2, A double-
// buffered depth-1. Per chunk: 7 dma16 (5 B + 2 A), 7 ds_read_b128,
// 10 MFMA (B frags amortized over 2 m-tiles).
// vmcnt queue order B(c),A(c),B(c+1),A(c+1),B(c+2): steady waitv<12>
// leaves exactly {B(c+1),A(c+1),B(c+2)} in flight; tails 7/0.
// ---------------------------------------------------------------------------
template<int NC, int ATILE>
__device__ __forceinline__ void gemm_dma32(
    const unsigned short* __restrict__ srcA, const unsigned short* __restrict__ srcB,
    unsigned short (*__restrict__ bufB)[2560], unsigned short (*__restrict__ bufA)[1024],
    int lane, int bl, f32x4 (&acc)[2][5])
{
#define DMB(c) { _Pragma("unroll")                                           \
        for (int i = 0; i < 5; ++i)                                          \
            dma16(srcB + (size_t)(c) * 2560 + i * 512 + lane * 8,            \
                  &bufB[(c) % 3][i * 512]); }
#define DMA_(c) {                                                            \
        dma16(srcA + (size_t)(c) * 512 + lane * 8, &bufA[(c) & 1][0]);       \
        dma16(srcA + ATILE + (size_t)(c) * 512 + lane * 8, &bufA[(c) & 1][512]); }
    DMB(0); DMA_(0); DMB(1);
#pragma unroll
    for (int c = 0; c < NC; ++c) {
        if (c + 1 < NC) DMA_(c + 1);
        if (c + 2 < NC) DMB(c + 2);
        if (c + 2 < NC)      waitv<12>();
        else if (c + 1 < NC) waitv<7>();
        else                 waitv<0>();
        bf16x8 af0 = *(const bf16x8*)(&bufA[c & 1][0]   + bl);
        bf16x8 af1 = *(const bf16x8*)(&bufA[c & 1][512] + bl);
        const unsigned short* bb = &bufB[c % 3][0];
#pragma unroll
        for (int t = 0; t < 5; ++t) {
            bf16x8 bf = *(const bf16x8*)(bb + t * 512 + bl);
            acc[0][t] = __builtin_amdgcn_mfma_f32_16x16x32_bf16(af0, bf, acc[0][t], 0, 0, 0);
            acc[1][t] = __builtin_amdgcn_mfma_f32_16x16x32_bf16(af1, bf, acc[1][t], 0, 0, 0);
        }
    }
#undef DMB
#undef DMA_
}

// ---------------------------------------------------------------------------
// Token kernel: 512 blocks x 128 thr (wave = ngrp half; block = 32 rows x
// one weight panel). 38 KB LDS -> 4 blocks/CU = 8 waves/CU (same as R1).
// XCD-aware mapping: x=b&7 is the XCD under round-robin dispatch; all 3
// gidx panels of one A-strip share an XCD (per-XCD set ~2.3 MB < 4 MB L2).
//   b <  384 : r=b>>3: gidx=r%3, mb32=(r/3)*8+x   (states, K=1024, NC=32)
//   b >= 384 : e=b-384: mb32=(e>>3)*8+(e&7)       (embeds x V, K=512)
// gidx==0 blocks fuse the attention tail (R6-verified): h1 -> LDS ->
// per-wave 16-token layer2 MFMA + layer3 reduce. No P0 round trip.
// ---------------------------------------------------------------------------
__global__ __launch_bounds__(128) void token_kernel(
    const unsigned short* __restrict__ Sb, const unsigned short* __restrict__ Eb,
    const unsigned short* __restrict__ wp, unsigned short* __restrict__ Pb,
    const float* __restrict__ ba1, const float* __restrict__ ba2,
    const float* __restrict__ Wa3, const float* __restrict__ ba3,
    float* __restrict__ attns)
{
    __shared__ __align__(16) unsigned short bufB[2][3][2560];   // 30 KB
    __shared__ __align__(16) unsigned short bufA[2][2][1024];   //  8 KB

    const int wv = threadIdx.x >> 6;                 // = ngrp
    const int lane = threadIdx.x & 63, l15 = lane & 15, quad = lane >> 4;
    const int bl = l15 * 32 + ((quad ^ ((l15 >> 1) & 3)) * 8);
    const int b = blockIdx.x;

    f32x4 acc[2][5];
#pragma unroll
    for (int mt = 0; mt < 2; ++mt)
#pragma unroll
        for (int t = 0; t < 5; ++t)
#pragma unroll
            for (int i = 0; i < 4; ++i) acc[mt][t][i] = 0.f;

    int mb32, gidx;
    if (b < 384) {
        const int x = b & 7, r = b >> 3;             // r in [0,48)
        gidx = r % 3;
        mb32 = (r / 3) * 8 + x;                      // [0,128)
        const unsigned short* srcA = Sb + (size_t)mb32 * 32768;
        const unsigned short* srcB = wp + WP_ST + gidx * 163840 + wv * 81920;
        gemm_dma32<32, 16384>(srcA, srcB, bufB[wv], bufA[wv], lane, bl, acc);
    } else {
        const int e = b - 384;                       // [0,128)
        mb32 = (e >> 3) * 8 + (e & 7);
        gidx = 3;                                    // V -> P3
        const unsigned short* srcA = Eb + (size_t)mb32 * 16384;
        const unsigned short* srcB = wp + WP_V + wv * 40960;
        gemm_dma32<16, 8192>(srcA, srcB, bufB[wv], bufA[wv], lane, bl, acc);
    }

    if (gidx == 0) {
        // ---- fused attention tail for tokens mb32*32 .. +31 ----
        unsigned short (*sHb)[168] = (unsigned short (*)[168])&bufB[0][0][0];
        __syncthreads();   // both waves' gemm done before aliasing bufB
#pragma unroll
        for (int mt = 0; mt < 2; ++mt)
#pragma unroll
            for (int t = 0; t < 5; ++t) {
                const int col = wv * 80 + t * 16 + l15;
                const float b1 = (col < HID) ? ba1[col] : 0.f;
#pragma unroll
                for (int i = 0; i < 4; ++i)
                    sHb[mt * 16 + quad * 4 + i][col] =
                        (col < HID) ? f2bf(fmaxf(acc[mt][t][i] + b1, 0.f))
                                    : (unsigned short)0;
            }
        __syncthreads();
        // per-wave: 16 tokens (rows wv*16..+15), layer2 MFMA + layer3
        const int t0 = mb32 * 32 + wv * 16;
        f32x4 a2[10];
#pragma unroll
        for (int nt = 0; nt < 10; ++nt)
#pragma unroll
            for (int i = 0; i < 4; ++i) a2[nt][i] = 0.f;

        const unsigned short* prow = &sHb[wv * 16 + l15][0];
        const unsigned short* bb = wp + WP_A2 + l15 * KP2 + quad * 8;
#pragma unroll
        for (int c = 0; c < 5; ++c) {
            const int k0 = c * 32;
            bf16x8 af = *(const bf16x8*)(prow + k0 + quad * 8);
#pragma unroll
            for (int nt = 0; nt < 10; ++nt) {
                bf16x8 bf = *(const bf16x8*)(bb + nt * 16 * KP2 + k0);
                a2[nt] = __builtin_amdgcn_mfma_f32_16x16x32_bf16(af, bf, a2[nt], 0, 0, 0);
            }
        }
        float sc[4] = {0.f, 0.f, 0.f, 0.f};
#pragma unroll
        for (int nt = 0; nt < 10; ++nt) {
            const int col = nt * 16 + l15;
            const float w3 = (col < HID) ? Wa3[col] : 0.f;
            const float b2 = (col < HID) ? ba2[col] : 0.f;
#pragma unroll
            for (int i = 0; i < 4; ++i)
                sc[i] = fmaf(fmaxf(a2[nt][i] + b2, 0.f), w3, sc[i]);
        }
#pragma unroll
        for (int off = 8; off >= 1; off >>= 1)
#pragma unroll
            for (int i = 0; i < 4; ++i) sc[i] += __shfl_down(sc[i], off, 16);
        if (l15 == 0) {
            const float b3 = ba3[0];
#pragma unroll
            for (int i = 0; i < 4; ++i) attns[t0 + quad * 4 + i] = sc[i] + b3;
        }
    } else {
        unsigned short* Pg = Pb + (size_t)gidx * 655360;
#pragma unroll
        for (int mt = 0; mt < 2; ++mt)
#pragma unroll
            for (int t = 0; t < 5; ++t) {
                const int col = wv * 80 + t * 16 + l15;
#pragma unroll
                for (int i = 0; i < 4; ++i)
                    Pg[(size_t)(mb32 * 32 + mt * 16 + quad * 4 + i) * PR + col] =
                        (col < HID) ? f2bf(acc[mt][t][i]) : (unsigned short)0;
            }
    }
}

// ---------------------------------------------------------------------------
// Span kernel: 32 spans/block, grid 1024, with in-block width rank-sort.
// ---------------------------------------------------------------------------
__global__ __launch_bounds__(256) void span_kernel(
    const unsigned short* __restrict__ Pb, const float* __restrict__ attns,
    const unsigned short* __restrict__ wp,
    const int* __restrict__ span_starts, const int* __restrict__ span_widths,
    const float* __restrict__ bs1, const float* __restrict__ bs2,
    const float* __restrict__ Ws3, const float* __restrict__ bs3,
    float* __restrict__ out)
{
    __shared__ unsigned short sHb[32][168];
    __shared__ float s_wgt[32][W_MAX];
    __shared__ int s_st[32], s_wd[32], s_bin[32], s_oid[32], s_wdr[32];
    __shared__ float sPart[4][32];
    __shared__ float sb1[KP2];

    const int tid = threadIdx.x;
    const int n0s = blockIdx.x * 32;

    if (tid < KP2) sb1[tid] = (tid < HID) ? bs1[tid] : 0.f;
    int st = 0, wd = 0;
    if (tid < 32) {
        st = span_starts[n0s + tid];
        wd = span_widths[n0s + tid];
        s_wdr[tid] = wd;
    }
    __syncthreads();
    if (tid < 32) {
        int rank = 0;
#pragma unroll
        for (int j = 0; j < 32; ++j) {
            const int wj = s_wdr[j];
            rank += (wj < wd) || (wj == wd && j < tid);
        }
        s_st[rank] = st; s_wd[rank] = wd; s_oid[rank] = tid;
        s_bin[rank] = (wd >= 1) + (wd >= 2) + (wd >= 3) + (wd >= 4) +
                      (wd >= 8) + (wd >= 16) + (wd >= 32) + (wd >= 64);
        float lg[W_MAX];
        float m = -1e30f;
#pragma unroll
        for (int w = 0; w < W_MAX; ++w)
            if (w < wd) { float a = attns[st + w]; lg[w] = a; m = fmaxf(m, a); }
        float sum = 0.f;
#pragma unroll
        for (int w = 0; w < W_MAX; ++w) {
            float e = (w < wd) ? __expf(lg[w] - m) : 0.f;
            lg[w] = e; sum += e;
        }
        float inv = 1.f / sum;
#pragma unroll
        for (int w = 0; w < W_MAX; ++w) s_wgt[rank][w] = lg[w] * inv;
    }
    __syncthreads();

    // gather-combine: 8 lanes/span, bf16x8 chunks (spans width-sorted)
    {
        const unsigned short* P1b = Pb + PB_P1;
        const unsigned short* P2b = Pb + PB_P2;
        const unsigned short* P3b = Pb + PB_P3;
        const unsigned short* WEb = wp + WP_WE1;
        const int s = tid >> 3, jl = tid & 7;
        const int sst = s_st[s], swd = s_wd[s];
        const size_t rs = (size_t)sst * PR;
        const size_t re = (size_t)(sst + swd - 1) * PR;
        const size_t rb = (size_t)s_bin[s] * PR;
        for (int c = jl; c < 20; c += 8) {
            const int j = c * 8;
            bf16x8 u1 = *(const bf16x8*)(P1b + rs + j);
            bf16x8 u2 = *(const bf16x8*)(P2b + re + j);
            bf16x8 uw = *(const bf16x8*)(WEb + rb + j);
            float acc[8];
#pragma unroll
            for (int i = 0; i < 8; ++i)
                acc[i] = bf2f(u1[i]) + bf2f(u2[i]) + bf2f(uw[i]) + sb1[j + i];
#pragma unroll
            for (int w = 0; w < W_MAX; ++w) {
                if (w < swd) {
                    float wt = s_wgt[s][w];
                    bf16x8 uv = *(const bf16x8*)(P3b + rs + (size_t)w * PR + j);
#pragma unroll
                    for (int i = 0; i < 8; ++i)
                        acc[i] = fmaf(wt, bf2f(uv[i]), acc[i]);
                }
            }
            bf16x8 pk;
#pragma unroll
            for (int i = 0; i < 8; ++i) pk[i] = (short)f2bf(fmaxf(acc[i], 0.f));
            *(bf16x8*)&sHb[s][j] = pk;
        }
    }
    __syncthreads();

    // layer2 MFMA: M=32 (2 m-tiles), N=160 (tiles 3,3,2,2 over waves)
    const int wv = tid >> 6, lane = tid & 63, l15 = lane & 15, quad = lane >> 4;
    const int nb = (wv < 2) ? wv * 3 : 6 + (wv - 2) * 2;
    const int cnt = (wv < 2) ? 3 : 2;

    f32x4 a2[2][3];
#pragma unroll
    for (int mt = 0; mt < 2; ++mt)
#pragma unroll
        for (int t = 0; t < 3; ++t)
#pragma unroll
            for (int i = 0; i < 4; ++i) a2[mt][t][i] = 0.f;

#pragma unroll
    for (int c = 0; c < 5; ++c) {
        int k0 = c * 32;
        bf16x8 af0 = *(const bf16x8*)&sHb[l15][k0 + quad * 8];
        bf16x8 af1 = *(const bf16x8*)&sHb[16 + l15][k0 + quad * 8];
#pragma unroll
        for (int t = 0; t < 3; ++t) {
            if (t < cnt) {
                bf16x8 b = *(const bf16x8*)(wp + WP_S2 +
                            (size_t)((nb + t) * 16 + l15) * KP2 + k0 + quad * 8);
                a2[0][t] = __builtin_amdgcn_mfma_f32_16x16x32_bf16(af0, b, a2[0][t], 0, 0, 0);
                a2[1][t] = __builtin_amdgcn_mfma_f32_16x16x32_bf16(af1, b, a2[1][t], 0, 0, 0);
            }
        }
    }

    float sc[2][4];
#pragma unroll
    for (int mt = 0; mt < 2; ++mt)
#pragma unroll
        for (int i = 0; i < 4; ++i) sc[mt][i] = 0.f;
#pragma unroll
    for (int t = 0; t < 3; ++t) {
        if (t < cnt) {
            int col = (nb + t) * 16 + l15;
            float w3 = (col < HID) ? Ws3[col] : 0.f;
            float b2 = (col < HID) ? bs2[col] : 0.f;
#pragma unroll
            for (int mt = 0; mt < 2; ++mt)
#pragma unroll
                for (int i = 0; i < 4; ++i)
                    sc[mt][i] = fmaf(fmaxf(a2[mt][t][i] + b2, 0.f), w3, sc[mt][i]);
        }
    }
#pragma unroll
    for (int off = 8; off >= 1; off >>= 1)
#pragma unroll
        for (int mt = 0; mt < 2; ++mt)
#pragma unroll
            for (int i = 0; i < 4; ++i)
                sc[mt][i] += __shfl_down(sc[mt][i], off, 16);
    if (l15 == 0) {
#pragma unroll
        for (int mt = 0; mt < 2; ++mt)
#pragma unroll
            for (int i = 0; i < 4; ++i)
                sPart[wv][mt * 16 + quad * 4 + i] = sc[mt][i];
    }
    __syncthreads();
    if (tid < 32)
        out[n0s + s_oid[tid]] = sPart[0][tid] + sPart[1][tid] + sPart[2][tid] +
                                sPart[3][tid] + bs3[0];
}

// ---------------------------------------------------------------------------
extern "C" void kernel_launch(void* const* d_in, const int* in_sizes, int n_in,
                              void* d_out, int out_size, void* d_ws, size_t ws_size,
                              hipStream_t stream)
{
    const float* states      = (const float*)d_in[0];
    const float* embeds      = (const float*)d_in[1];
    const int*   span_starts = (const int*)d_in[2];
    const int*   span_widths = (const int*)d_in[3];
    const float* Wa1 = (const float*)d_in[4];
    const float* ba1 = (const float*)d_in[5];
    const float* Wa2 = (const float*)d_in[6];
    const float* ba2 = (const float*)d_in[7];
    const float* Wa3 = (const float*)d_in[8];
    const float* ba3 = (const float*)d_in[9];
    const float* width_emb = (const float*)d_in[10];
    const float* Ws1 = (const float*)d_in[11];
    const float* bs1 = (const float*)d_in[12];
    const float* Ws2 = (const float*)d_in[13];
    const float* bs2 = (const float*)d_in[14];
    const float* Ws3 = (const float*)d_in[15];
    const float* bs3 = (const float*)d_in[16];
    float* out = (float*)d_out;

    float* ws    = (float*)d_ws;
    float* attns = ws + WS_ATTNS;
    unsigned short* Pb    = (unsigned short*)(ws + WS_PB);
    unsigned short* wpack = (unsigned short*)(ws + WS_WPACK);
    unsigned short* Sb    = (unsigned short*)(ws + WS_SB);
    unsigned short* Eb    = (unsigned short*)(ws + WS_EB);

    hipLaunchKernelGGL(prepack_kernel, dim3((PK_ITEMS + 255) / 256), dim3(256), 0, stream,
                       states, embeds, Wa1, Ws1, Wa2, Ws2, width_emb,
                       wpack, Sb, Eb);
    hipLaunchKernelGGL(token_kernel, dim3(512), dim3(128), 0, stream,
                       Sb, Eb, wpack, Pb, ba1, ba2, Wa3, ba3, attns);
    hipLaunchKernelGGL(span_kernel, dim3(N_SPAN / 32), dim3(256), 0, stream,
                       Pb, attns, wpack, span_starts, span_widths,
                       bs1, bs2, Ws3, bs3, out);
}

// Round 9
// 146.159 us; speedup vs baseline: 4.7483x; 1.0019x over previous
//
#include <hip/hip_runtime.h>
#include <math.h>

#define T_TOK 4096
#define A_DIM 1024
#define E_DIM 512
#define N_SPAN 32768
#define W_MAX 10
#define HID 150
#define FD 20

#define PR  160             // P row stride (bf16 elems); cols 150..159 zero
#define KP2 160             // padded K/N for the 150x150 layers

// ---- workspace layout (float offsets) ----
#define WS_ATTNS 0
#define WS_PB    4096
#define WS_WPACK 1314816
#define WS_SB    1627856
#define WS_EB    3725008
// Pb ushort offsets (P0 slot unused: attn fused in token)
#define PB_P0 0
#define PB_P1 655360
#define PB_P2 1310720
#define PB_P3 1966080
// wpack ushort offsets
//   ST: [3 gidx][2 ngrp][32 c][2560]  (chunk-contiguous, XOR-swizzled)
//   V : [2 ngrp][16 c][2560]
//   A2/S2: [160 n][160 k] n-major;  WE1: [9][160]
#define WP_ST  0
#define WP_V   491520
#define WP_A2  573440
#define WP_S2  599040
#define WP_WE1 624640
#define WP_TOTAL 626080
#define SB_PIECES 524288     // 4096*1024/8
#define EB_PIECES 262144     // 4096*512/8
#define PK_ITEMS (WP_TOTAL + SB_PIECES + EB_PIECES)

typedef short  bf16x8 __attribute__((ext_vector_type(8)));
typedef float  f32x4  __attribute__((ext_vector_type(4)));

__device__ __forceinline__ float4 ld4(const float* p) { return *(const float4*)p; }

__device__ __forceinline__ unsigned short f2bf(float f) {
    unsigned u = __float_as_uint(f);
    unsigned r = u + 0x7fffu + ((u >> 16) & 1u);   // RNE
    return (unsigned short)(r >> 16);
}
__device__ __forceinline__ float bf2f(short s) {
    return __uint_as_float(((unsigned)(unsigned short)s) << 16);
}
__device__ __forceinline__ bf16x8 cvt_frag(const float* p) {
    float4 u = ld4(p), v = ld4(p + 4);
    bf16x8 f;
    f[0] = (short)f2bf(u.x); f[1] = (short)f2bf(u.y);
    f[2] = (short)f2bf(u.z); f[3] = (short)f2bf(u.w);
    f[4] = (short)f2bf(v.x); f[5] = (short)f2bf(v.y);
    f[6] = (short)f2bf(v.z); f[7] = (short)f2bf(v.w);
    return f;
}

// async global->LDS, 16 B/lane; LDS dst = wave-uniform base + lane*16
typedef const __attribute__((address_space(1))) unsigned int as1_u32;
typedef __attribute__((address_space(3))) unsigned int as3_u32;
__device__ __forceinline__ void dma16(const void* g, void* l) {
    __builtin_amdgcn_global_load_lds((as1_u32*)g, (as3_u32*)l, 16, 0, 0);
}
template<int N> __device__ __forceinline__ void waitv() {
    asm volatile("s_waitcnt vmcnt(%0)" :: "n"(N) : "memory");
}

// ---------------------------------------------------------------------------
// Prepack (dst-linear, coalesced writes): weights + Sb/Eb bf16 staging.
// ---------------------------------------------------------------------------
__global__ __launch_bounds__(256) void prepack_kernel(
    const float* __restrict__ states, const float* __restrict__ embeds,
    const float* __restrict__ Wa1, const float* __restrict__ Ws1,
    const float* __restrict__ Wa2, const float* __restrict__ Ws2,
    const float* __restrict__ width_emb,
    unsigned short* __restrict__ wp, unsigned short* __restrict__ Sb,
    unsigned short* __restrict__ Eb)
{
    int idx = blockIdx.x * 256 + threadIdx.x;
    if (idx >= PK_ITEMS) return;
    if (idx < WP_TOTAL) {
        float v = 0.f;
        if (idx < WP_V) {                               // ST: 3 x 2 x 32 x 2560
            int gidx = idx / 163840, r = idx % 163840;
            int ngrp = r / 81920, r2 = r % 81920;
            int c = r2 / 2560, d = r2 % 2560;
            int n = d >> 5, qsw = (d >> 3) & 3, off = d & 7;
            int q = qsw ^ ((n >> 1) & 3);
            int k = c * 32 + q * 8 + off;
            int gn = ngrp * 80 + n;
            const float* W = (gidx == 0) ? Wa1 : Ws1 + (size_t)(gidx - 1) * 1024 * HID;
            if (gn < HID) v = W[(size_t)k * HID + gn];
        } else if (idx < WP_A2) {                       // V: 2 x 16 x 2560
            int r = idx - WP_V;
            int ngrp = r / 40960, r2 = r % 40960;
            int c = r2 / 2560, d = r2 % 2560;
            int n = d >> 5, qsw = (d >> 3) & 3, off = d & 7;
            int q = qsw ^ ((n >> 1) & 3);
            int k = c * 32 + q * 8 + off;
            int gn = ngrp * 80 + n;
            if (gn < HID) v = Ws1[(size_t)(2048 + k) * HID + gn];
        } else if (idx < WP_S2) {                       // Wa2 [n][160]
            int e = idx - WP_A2;
            int n = e / KP2, k = e % KP2;
            if (n < HID && k < HID) v = Wa2[(size_t)k * HID + n];
        } else if (idx < WP_WE1) {                      // Ws2 [n][160]
            int e = idx - WP_S2;
            int n = e / KP2, k = e % KP2;
            if (n < HID && k < HID) v = Ws2[(size_t)k * HID + n];
        } else {                                        // WE1 [9][160]
            int e = idx - WP_WE1;
            int b = e / KP2, n = e % KP2;
            if (n < HID)
                for (int k = 0; k < FD; ++k)
                    v = fmaf(width_emb[b * FD + k], Ws1[(size_t)(2560 + k) * HID + n], v);
        }
        wp[idx] = f2bf(v);
    } else if (idx < WP_TOTAL + SB_PIECES) {            // Sb piece (8 elems)
        int p = idx - WP_TOTAL;
        int mb = p >> 11, r = p & 2047;                 // 2048 pieces per 16-row tile
        int c = r >> 6, d8 = r & 63;
        int m = d8 >> 2, qsw = d8 & 3;
        int q = qsw ^ ((m >> 1) & 3);
        const float* src = states + (size_t)(mb * 16 + m) * A_DIM + c * 32 + q * 8;
        *(bf16x8*)(Sb + (size_t)p * 8) = cvt_frag(src);
    } else {                                            // Eb piece
        int p = idx - WP_TOTAL - SB_PIECES;
        int mb = p >> 10, r = p & 1023;                 // 1024 pieces per tile
        int c = r >> 6, d8 = r & 63;
        int m = d8 >> 2, qsw = d8 & 3;
        int q = qsw ^ ((m >> 1) & 3);
        const float* src = embeds + (size_t)(mb * 16 + m) * E_DIM + c * 32 + q * 8;
        *(bf16x8*)(Eb + (size_t)p * 8) = cvt_frag(src);
    }
}

// ---------------------------------------------------------------------------
// Hybrid M=32 GEMM strip: B via dma16 (DMA engine), A via coalesced
// register loads from Sb/Eb (vector path). Per chunk: 5 dma + 2 reg-loads,
// 10 MFMA. B triple-buffered depth-2; A double-buffered in regs.
// Mixed vmcnt queue (issue order B(c+2)x5 then A(c+1)x2):
//   steady waitv<7>  -> B(c) in LDS and A(c) in regs;
//   tail  waitv<2>, waitv<0>.
// ---------------------------------------------------------------------------
template<int NC>
__device__ __forceinline__ void gemm_hyb(
    const unsigned short* __restrict__ pA0, const unsigned short* __restrict__ pA1,
    const unsigned short* __restrict__ srcB, unsigned short (*__restrict__ bufB)[2560],
    int lane, int bl, f32x4 (&acc)[2][5])
{
    bf16x8 a0[2], a1[2];
#define DMB(c) { _Pragma("unroll")                                           \
        for (int i = 0; i < 5; ++i)                                          \
            dma16(srcB + (size_t)(c) * 2560 + i * 512 + lane * 8,            \
                  &bufB[(c) % 3][i * 512]); }
#define LDA_(c, s) { a0[s] = *(const bf16x8*)(pA0 + (size_t)(c) * 512);      \
                     a1[s] = *(const bf16x8*)(pA1 + (size_t)(c) * 512); }
    DMB(0); DMB(1); LDA_(0, 0);
#pragma unroll
    for (int c = 0; c < NC; ++c) {
        const int s = c & 1;
        if (c + 2 < NC) DMB(c + 2);
        if (c + 1 < NC) LDA_(c + 1, s ^ 1);
        if (c + 2 < NC)      waitv<7>();
        else if (c + 1 < NC) waitv<2>();
        else                 waitv<0>();
        const unsigned short* bb = &bufB[c % 3][0];
#pragma unroll
        for (int t = 0; t < 5; ++t) {
            bf16x8 bf = *(const bf16x8*)(bb + t * 512 + bl);
            acc[0][t] = __builtin_amdgcn_mfma_f32_16x16x32_bf16(a0[s], bf, acc[0][t], 0, 0, 0);
            acc[1][t] = __builtin_amdgcn_mfma_f32_16x16x32_bf16(a1[s], bf, acc[1][t], 0, 0, 0);
        }
    }
#undef DMB
#undef LDA_
}

// ---------------------------------------------------------------------------
// Token kernel: 512 blocks x 128 thr (wave = ngrp half; block = 32 rows x
// one weight panel). 30 KB LDS. DMA pipe carries ONLY B (143 MB total);
// A rides the register path from prepacked Sb/Eb.
//   b <  384 : gidx=b%3, mb32=b/3   (states, K=1024, NC=32)
//   b >= 384 : mb32=b-384           (embeds x V -> P3, K=512, NC=16)
// gidx==0 blocks fuse the attention tail (R7-verified): h1 -> LDS ->
// per-wave 16-token layer2 MFMA + layer3 reduce. No P0 round trip.
// ---------------------------------------------------------------------------
__global__ __launch_bounds__(128) void token_kernel(
    const unsigned short* __restrict__ Sb, const unsigned short* __restrict__ Eb,
    const unsigned short* __restrict__ wp, unsigned short* __restrict__ Pb,
    const float* __restrict__ ba1, const float* __restrict__ ba2,
    const float* __restrict__ Wa3, const float* __restrict__ ba3,
    float* __restrict__ attns)
{
    __shared__ __align__(16) unsigned short bufB[2][3][2560];   // 30 KB

    const int wv = threadIdx.x >> 6;                 // = ngrp
    const int lane = threadIdx.x & 63, l15 = lane & 15, quad = lane >> 4;
    const int bl = l15 * 32 + ((quad ^ ((l15 >> 1) & 3)) * 8);
    const int b = blockIdx.x;

    f32x4 acc[2][5];
#pragma unroll
    for (int mt = 0; mt < 2; ++mt)
#pragma unroll
        for (int t = 0; t < 5; ++t)
#pragma unroll
            for (int i = 0; i < 4; ++i) acc[mt][t][i] = 0.f;

    int mb32, gidx;
    if (b < 384) {
        gidx = b % 3;                                // 0:Wa1(fused attn) 1:P1 2:P2
        mb32 = b / 3;                                // [0,128)
        const unsigned short* pA0 = Sb + (size_t)(mb32 * 2) * 16384 + bl;
        const unsigned short* pA1 = pA0 + 16384;
        const unsigned short* srcB = wp + WP_ST + gidx * 163840 + wv * 81920;
        gemm_hyb<32>(pA0, pA1, srcB, bufB[wv], lane, bl, acc);
    } else {
        mb32 = b - 384;                              // [0,128)
        gidx = 3;                                    // V -> P3
        const unsigned short* pA0 = Eb + (size_t)(mb32 * 2) * 8192 + bl;
        const unsigned short* pA1 = pA0 + 8192;
        const unsigned short* srcB = wp + WP_V + wv * 40960;
        gemm_hyb<16>(pA0, pA1, srcB, bufB[wv], lane, bl, acc);
    }

    if (gidx == 0) {
        // ---- fused attention tail for tokens mb32*32 .. +31 ----
        unsigned short (*sHb)[168] = (unsigned short (*)[168])&bufB[0][0][0];
        __syncthreads();   // both waves' gemm done before aliasing bufB
#pragma unroll
        for (int mt = 0; mt < 2; ++mt)
#pragma unroll
            for (int t = 0; t < 5; ++t) {
                const int col = wv * 80 + t * 16 + l15;
                const float b1 = (col < HID) ? ba1[col] : 0.f;
#pragma unroll
                for (int i = 0; i < 4; ++i)
                    sHb[mt * 16 + quad * 4 + i][col] =
                        (col < HID) ? f2bf(fmaxf(acc[mt][t][i] + b1, 0.f))
                                    : (unsigned short)0;
            }
        __syncthreads();
        // per-wave: 16 tokens (rows wv*16..+15), layer2 MFMA + layer3
        const int t0 = mb32 * 32 + wv * 16;
        f32x4 a2[10];
#pragma unroll
        for (int nt = 0; nt < 10; ++nt)
#pragma unroll
            for (int i = 0; i < 4; ++i) a2[nt][i] = 0.f;

        const unsigned short* prow = &sHb[wv * 16 + l15][0];
        const unsigned short* bb = wp + WP_A2 + l15 * KP2 + quad * 8;
#pragma unroll
        for (int c = 0; c < 5; ++c) {
            const int k0 = c * 32;
            bf16x8 af = *(const bf16x8*)(prow + k0 + quad * 8);
#pragma unroll
            for (int nt = 0; nt < 10; ++nt) {
                bf16x8 bf = *(const bf16x8*)(bb + nt * 16 * KP2 + k0);
                a2[nt] = __builtin_amdgcn_mfma_f32_16x16x32_bf16(af, bf, a2[nt], 0, 0, 0);
            }
        }
        float sc[4] = {0.f, 0.f, 0.f, 0.f};
#pragma unroll
        for (int nt = 0; nt < 10; ++nt) {
            const int col = nt * 16 + l15;
            const float w3 = (col < HID) ? Wa3[col] : 0.f;
            const float b2 = (col < HID) ? ba2[col] : 0.f;
#pragma unroll
            for (int i = 0; i < 4; ++i)
                sc[i] = fmaf(fmaxf(a2[nt][i] + b2, 0.f), w3, sc[i]);
        }
#pragma unroll
        for (int off = 8; off >= 1; off >>= 1)
#pragma unroll
            for (int i = 0; i < 4; ++i) sc[i] += __shfl_down(sc[i], off, 16);
        if (l15 == 0) {
            const float b3 = ba3[0];
#pragma unroll
            for (int i = 0; i < 4; ++i) attns[t0 + quad * 4 + i] = sc[i] + b3;
        }
    } else {
        unsigned short* Pg = Pb + (size_t)gidx * 655360;
#pragma unroll
        for (int mt = 0; mt < 2; ++mt)
#pragma unroll
            for (int t = 0; t < 5; ++t) {
                const int col = wv * 80 + t * 16 + l15;
#pragma unroll
                for (int i = 0; i < 4; ++i)
                    Pg[(size_t)(mb32 * 32 + mt * 16 + quad * 4 + i) * PR + col] =
                        (col < HID) ? f2bf(acc[mt][t][i]) : (unsigned short)0;
            }
    }
}

// ---------------------------------------------------------------------------
// Span kernel: 32 spans/block, grid 1024, with in-block width rank-sort.
// ---------------------------------------------------------------------------
__global__ __launch_bounds__(256) void span_kernel(
    const unsigned short* __restrict__ Pb, const float* __restrict__ attns,
    const unsigned short* __restrict__ wp,
    const int* __restrict__ span_starts, const int* __restrict__ span_widths,
    const float* __restrict__ bs1, const float* __restrict__ bs2,
    const float* __restrict__ Ws3, const float* __restrict__ bs3,
    float* __restrict__ out)
{
    __shared__ unsigned short sHb[32][168];
    __shared__ float s_wgt[32][W_MAX];
    __shared__ int s_st[32], s_wd[32], s_bin[32], s_oid[32], s_wdr[32];
    __shared__ float sPart[4][32];
    __shared__ float sb1[KP2];

    const int tid = threadIdx.x;
    const int n0s = blockIdx.x * 32;

    if (tid < KP2) sb1[tid] = (tid < HID) ? bs1[tid] : 0.f;
    int st = 0, wd = 0;
    if (tid < 32) {
        st = span_starts[n0s + tid];
        wd = span_widths[n0s + tid];
        s_wdr[tid] = wd;
    }
    __syncthreads();
    if (tid < 32) {
        int rank = 0;
#pragma unroll
        for (int j = 0; j < 32; ++j) {
            const int wj = s_wdr[j];
            rank += (wj < wd) || (wj == wd && j < tid);
        }
        s_st[rank] = st; s_wd[rank] = wd; s_oid[rank] = tid;
        s_bin[rank] = (wd >= 1) + (wd >= 2) + (wd >= 3) + (wd >= 4) +
                      (wd >= 8) + (wd >= 16) + (wd >= 32) + (wd >= 64);
        float lg[W_MAX];
        float m = -1e30f;
#pragma unroll
        for (int w = 0; w < W_MAX; ++w)
            if (w < wd) { float a = attns[st + w]; lg[w] = a; m = fmaxf(m, a); }
        float sum = 0.f;
#pragma unroll
        for (int w = 0; w < W_MAX; ++w) {
            float e = (w < wd) ? __expf(lg[w] - m) : 0.f;
            lg[w] = e; sum += e;
        }
        float inv = 1.f / sum;
#pragma unroll
        for (int w = 0; w < W_MAX; ++w) s_wgt[rank][w] = lg[w] * inv;
    }
    __syncthreads();

    // gather-combine: 8 lanes/span, bf16x8 chunks (spans width-sorted)
    {
        const unsigned short* P1b = Pb + PB_P1;
        const unsigned short* P2b = Pb + PB_P2;
        const unsigned short* P3b = Pb + PB_P3;
        const unsigned short* WEb = wp + WP_WE1;
        const int s = tid >> 3, jl = tid & 7;
        const int sst = s_st[s], swd = s_wd[s];
        const size_t rs = (size_t)sst * PR;
        const size_t re = (size_t)(sst + swd - 1) * PR;
        const size_t rb = (size_t)s_bin[s] * PR;
        for (int c = jl; c < 20; c += 8) {
            const int j = c * 8;
            bf16x8 u1 = *(const bf16x8*)(P1b + rs + j);
            bf16x8 u2 = *(const bf16x8*)(P2b + re + j);
            bf16x8 uw = *(const bf16x8*)(WEb + rb + j);
            float acc[8];
#pragma unroll
            for (int i = 0; i < 8; ++i)
                acc[i] = bf2f(u1[i]) + bf2f(u2[i]) + bf2f(uw[i]) + sb1[j + i];
#pragma unroll
            for (int w = 0; w < W_MAX; ++w) {
                if (w < swd) {
                    float wt = s_wgt[s][w];
                    bf16x8 uv = *(const bf16x8*)(P3b + rs + (size_t)w * PR + j);
#pragma unroll
                    for (int i = 0; i < 8; ++i)
                        acc[i] = fmaf(wt, bf2f(uv[i]), acc[i]);
                }
            }
            bf16x8 pk;
#pragma unroll
            for (int i = 0; i < 8; ++i) pk[i] = (short)f2bf(fmaxf(acc[i], 0.f));
            *(bf16x8*)&sHb[s][j] = pk;
        }
    }
    __syncthreads();

    // layer2 MFMA: M=32 (2 m-tiles), N=160 (tiles 3,3,2,2 over waves)
    const int wv = tid >> 6, lane = tid & 63, l15 = lane & 15, quad = lane >> 4;
    const int nb = (wv < 2) ? wv * 3 : 6 + (wv - 2) * 2;
    const int cnt = (wv < 2) ? 3 : 2;

    f32x4 a2[2][3];
#pragma unroll
    for (int mt = 0; mt < 2; ++mt)
#pragma unroll
        for (int t = 0; t < 3; ++t)
#pragma unroll
            for (int i = 0; i < 4; ++i) a2[mt][t][i] = 0.f;

#pragma unroll
    for (int c = 0; c < 5; ++c) {
        int k0 = c * 32;
        bf16x8 af0 = *(const bf16x8*)&sHb[l15][k0 + quad * 8];
        bf16x8 af1 = *(const bf16x8*)&sHb[16 + l15][k0 + quad * 8];
#pragma unroll
        for (int t = 0; t < 3; ++t) {
            if (t < cnt) {
                bf16x8 b = *(const bf16x8*)(wp + WP_S2 +
                            (size_t)((nb + t) * 16 + l15) * KP2 + k0 + quad * 8);
                a2[0][t] = __builtin_amdgcn_mfma_f32_16x16x32_bf16(af0, b, a2[0][t], 0, 0, 0);
                a2[1][t] = __builtin_amdgcn_mfma_f32_16x16x32_bf16(af1, b, a2[1][t], 0, 0, 0);
            }
        }
    }

    float sc[2][4];
#pragma unroll
    for (int mt = 0; mt < 2; ++mt)
#pragma unroll
        for (int i = 0; i < 4; ++i) sc[mt][i] = 0.f;
#pragma unroll
    for (int t = 0; t < 3; ++t) {
        if (t < cnt) {
            int col = (nb + t) * 16 + l15;
            float w3 = (col < HID) ? Ws3[col] : 0.f;
            float b2 = (col < HID) ? bs2[col] : 0.f;
#pragma unroll
            for (int mt = 0; mt < 2; ++mt)
#pragma unroll
                for (int i = 0; i < 4; ++i)
                    sc[mt][i] = fmaf(fmaxf(a2[mt][t][i] + b2, 0.f), w3, sc[mt][i]);
        }
    }
#pragma unroll
    for (int off = 8; off >= 1; off >>= 1)
#pragma unroll
        for (int mt = 0; mt < 2; ++mt)
#pragma unroll
            for (int i = 0; i < 4; ++i)
                sc[mt][i] += __shfl_down(sc[mt][i], off, 16);
    if (l15 == 0) {
#pragma unroll
        for (int mt = 0; mt < 2; ++mt)
#pragma unroll
            for (int i = 0; i < 4; ++i)
                sPart[wv][mt * 16 + quad * 4 + i] = sc[mt][i];
    }
    __syncthreads();
    if (tid < 32)
        out[n0s + s_oid[tid]] = sPart[0][tid] + sPart[1][tid] + sPart[2][tid] +
                                sPart[3][tid] + bs3[0];
}

// ---------------------------------------------------------------------------
extern "C" void kernel_launch(void* const* d_in, const int* in_sizes, int n_in,
                              void* d_out, int out_size, void* d_ws, size_t ws_size,
                              hipStream_t stream)
{
    const float* states      = (const float*)d_in[0];
    const float* embeds      = (const float*)d_in[1];
    const int*   span_starts = (const int*)d_in[2];
    const int*   span_widths = (const int*)d_in[3];
    const float* Wa1 = (const float*)d_in[4];
    const float* ba1 = (const float*)d_in[5];
    const float* Wa2 = (const float*)d_in[6];
    const float* ba2 = (const float*)d_in[7];
    const float* Wa3 = (const float*)d_in[8];
    const float* ba3 = (const float*)d_in[9];
    const float* width_emb = (const float*)d_in[10];
    const float* Ws1 = (const float*)d_in[11];
    const float* bs1 = (const float*)d_in[12];
    const float* Ws2 = (const float*)d_in[13];
    const float* bs2 = (const float*)d_in[14];
    const float* Ws3 = (const float*)d_in[15];
    const float* bs3 = (const float*)d_in[16];
    float* out = (float*)d_out;

    float* ws    = (float*)d_ws;
    float* attns = ws + WS_ATTNS;
    unsigned short* Pb    = (unsigned short*)(ws + WS_PB);
    unsigned short* wpack = (unsigned short*)(ws + WS_WPACK);
    unsigned short* Sb    = (unsigned short*)(ws + WS_SB);
    unsigned short* Eb    = (unsigned short*)(ws + WS_EB);

    hipLaunchKernelGGL(prepack_kernel, dim3((PK_ITEMS + 255) / 256), dim3(256), 0, stream,
                       states, embeds, Wa1, Ws1, Wa2, Ws2, width_emb,
                       wpack, Sb, Eb);
    hipLaunchKernelGGL(token_kernel, dim3(512), dim3(128), 0, stream,
                       Sb, Eb, wpack, Pb, ba1, ba2, Wa3, ba3, attns);
    hipLaunchKernelGGL(span_kernel, dim3(N_SPAN / 32), dim3(256), 0, stream,
                       Pb, attns, wpack, span_starts, span_widths,
                       bs1, bs2, Ws3, bs3, out);
}